// Round 3
// baseline (15500.896 us; speedup 1.0000x reference)
//
#include <hip/hip_runtime.h>

// ---------------------------------------------------------------------------
// VITS-style relative-attention encoder, MI355X round 3.
// Change vs round 2: ALL inputs/outputs are float32 (reference is jnp.float32;
// the bf16-I/O hypothesis is falsified -- threshold arithmetic shows the
// harness floor_eps_k path was NOT taken, and fp32-read-as-bf16 exactly
// reproduces the observed NaN). Internal math fp32. Workspace 56 MiB.
// Rel-position terms are banded (|s-t| <= 10) since the embedding is
// zero-padded outside the window.
// ---------------------------------------------------------------------------

#define NLAYERS 6
#define BB 8
#define TT 512
#define CC 512
#define FF 2048
#define HH 8
#define DKK 64
#define WW 10

static_assert(CC == HH * DKK, "");

__device__ __forceinline__ float wave_sum(float v) {
    #pragma unroll
    for (int off = 32; off > 0; off >>= 1) v += __shfl_xor(v, off, 64);
    return v;
}
__device__ __forceinline__ float wave_max(float v) {
    #pragma unroll
    for (int off = 32; off > 0; off >>= 1) v = fmaxf(v, __shfl_xor(v, off, 64));
    return v;
}

// ---------------------------------------------------------------------------
__global__ __launch_bounds__(256) void init_kernel(const float* __restrict__ x,
                                                   const float* __restrict__ mask,
                                                   float* __restrict__ xf) {
    size_t i = (size_t)blockIdx.x * 256 + threadIdx.x;
    const size_t total = (size_t)BB * CC * TT;
    if (i >= total) return;
    int t = (int)(i % TT);
    int b = (int)(i / ((size_t)CC * TT));
    xf[i] = x[i] * mask[b * TT + t];
}

__global__ __launch_bounds__(256) void maskmul_kernel(const float* __restrict__ in,
                                                      const float* __restrict__ mask,
                                                      float* __restrict__ out) {
    size_t i = (size_t)blockIdx.x * 256 + threadIdx.x;
    const size_t total = (size_t)BB * CC * TT;
    if (i >= total) return;
    int t = (int)(i % TT);
    int b = (int)(i / ((size_t)CC * TT));
    out[i] = in[i] * mask[b * TT + t];
}

__global__ __launch_bounds__(256) void final_kernel(const float* __restrict__ xf,
                                                    const float* __restrict__ mask,
                                                    float* __restrict__ out) {
    size_t i = (size_t)blockIdx.x * 256 + threadIdx.x;
    const size_t total = (size_t)BB * CC * TT;
    if (i >= total) return;
    int t = (int)(i % TT);
    int b = (int)(i / ((size_t)CC * TT));
    out[i] = xf[i] * mask[b * TT + t];
}

// ---------------------------------------------------------------------------
// Out[b,o,t] = bias[o] + sum_{tap,c} A[o,c,tap] * X[b,c,t+tap-(ntaps>1)]
template <bool RELU_MASK>
__global__ __launch_bounds__(256) void gemm_kernel(const float* __restrict__ A,
                                                   const float* __restrict__ bias,
                                                   const float* __restrict__ X,
                                                   float* __restrict__ Out,
                                                   const float* __restrict__ mask,
                                                   int O, int K, int ntaps) {
    const int t0 = blockIdx.x * 64;
    const int o0 = blockIdx.y * 64;
    const int b  = blockIdx.z;
    const int tid = threadIdx.x;
    const int i0 = (tid >> 4) << 2;  // o sub-tile
    const int j0 = (tid & 15) << 2;  // t sub-tile

    __shared__ float As[16][64];  // [c][o]
    __shared__ float Xs[16][64];  // [c][t]
    float acc[4][4] = {};

    const int lda = K * ntaps;
    const float* Xb = X + (size_t)b * K * TT;

    for (int tap = 0; tap < ntaps; ++tap) {
        const int shift = (ntaps > 1) ? (tap - 1) : 0;
        for (int cc = 0; cc < K; cc += 16) {
            {
                const int ia = tid >> 2;
                const int j4 = (tid & 3) << 2;
                const float* Ap = A + (size_t)(o0 + ia) * lda + (size_t)(cc + j4) * ntaps + tap;
                #pragma unroll
                for (int j = 0; j < 4; ++j)
                    As[j4 + j][ia] = Ap[(size_t)j * ntaps];
            }
            {
                const int jr = tid >> 4;
                const int t4 = (tid & 15) << 2;
                const float* Xp = Xb + (size_t)(cc + jr) * TT;
                #pragma unroll
                for (int u = 0; u < 4; ++u) {
                    const int t = t0 + t4 + u + shift;
                    Xs[jr][t4 + u] = (t >= 0 && t < TT) ? Xp[t] : 0.f;
                }
            }
            __syncthreads();
            #pragma unroll
            for (int kk = 0; kk < 16; ++kk) {
                float a[4], xv[4];
                #pragma unroll
                for (int i = 0; i < 4; ++i) a[i] = As[kk][i0 + i];
                #pragma unroll
                for (int j = 0; j < 4; ++j) xv[j] = Xs[kk][j0 + j];
                #pragma unroll
                for (int i = 0; i < 4; ++i)
                    #pragma unroll
                    for (int j = 0; j < 4; ++j)
                        acc[i][j] += a[i] * xv[j];
            }
            __syncthreads();
        }
    }

    #pragma unroll
    for (int i = 0; i < 4; ++i) {
        const int o = o0 + i0 + i;
        const float bv = bias[o];
        float* Op = Out + ((size_t)b * O + o) * TT + t0 + j0;
        #pragma unroll
        for (int j = 0; j < 4; ++j) {
            float v = acc[i][j] + bv;
            if (RELU_MASK) v = fmaxf(v, 0.f) * mask[b * TT + t0 + j0 + j];
            Op[j] = v;
        }
    }
}

// ---------------------------------------------------------------------------
// Per-batch attention kernels. sc is [H, T, T] fp32 for batch `b`.
__global__ __launch_bounds__(256) void qk_kernel(const float* __restrict__ q,
                                                 const float* __restrict__ k,
                                                 const float* __restrict__ mask,
                                                 float* __restrict__ sc, int b) {
    const int s0 = blockIdx.x * 64;
    const int t0 = blockIdx.y * 64;
    const int h = blockIdx.z;
    const int tid = threadIdx.x;
    const int i0 = (tid >> 4) << 2;  // t
    const int j0 = (tid & 15) << 2;  // s

    __shared__ float Qs[16][64];
    __shared__ float Ks[16][64];
    float acc[4][4] = {};
    const size_t base = ((size_t)b * CC + h * DKK) * TT;

    for (int cc = 0; cc < DKK; cc += 16) {
        const int jr = tid >> 4;
        const int c4 = (tid & 15) << 2;
        const float* Qp = q + base + (size_t)(cc + jr) * TT + t0 + c4;
        const float* Kp = k + base + (size_t)(cc + jr) * TT + s0 + c4;
        #pragma unroll
        for (int u = 0; u < 4; ++u) {
            Qs[jr][c4 + u] = Qp[u];
            Ks[jr][c4 + u] = Kp[u];
        }
        __syncthreads();
        #pragma unroll
        for (int kk = 0; kk < 16; ++kk) {
            float a[4], bb_[4];
            #pragma unroll
            for (int i = 0; i < 4; ++i) a[i] = Qs[kk][i0 + i];
            #pragma unroll
            for (int j = 0; j < 4; ++j) bb_[j] = Ks[kk][j0 + j];
            #pragma unroll
            for (int i = 0; i < 4; ++i)
                #pragma unroll
                for (int j = 0; j < 4; ++j)
                    acc[i][j] += a[i] * bb_[j];
        }
        __syncthreads();
    }

    #pragma unroll
    for (int i = 0; i < 4; ++i) {
        const int t = t0 + i0 + i;
        const float mt = mask[b * TT + t];
        float* row = sc + ((size_t)h * TT + t) * TT + s0 + j0;
        #pragma unroll
        for (int j = 0; j < 4; ++j) {
            const float ms = mask[b * TT + s0 + j0 + j];
            row[j] = (mt * ms == 0.f) ? -1e4f : 0.125f * acc[i][j];
        }
    }
}

__global__ __launch_bounds__(64) void relk_kernel(const float* __restrict__ q,
                                                  const float* __restrict__ erk,
                                                  const float* __restrict__ mask,
                                                  float* __restrict__ sc, int b) {
    const int t = blockIdx.x;
    const int h = blockIdx.y;
    const int d = threadIdx.x;
    const float mt = mask[b * TT + t];
    const float qv = q[((size_t)b * CC + h * DKK + d) * TT + t];
    float* row = sc + ((size_t)h * TT + t) * TT;
    for (int w = 0; w < 2 * WW + 1; ++w) {
        const int s = t + w - WW;
        if (s < 0 || s >= TT) continue;
        const float part = qv * erk[w * DKK + d];
        const float sum = wave_sum(part);
        if (d == 0) {
            const float ms = mask[b * TT + s];
            if (mt * ms != 0.f) row[s] += 0.125f * sum;
        }
    }
}

__global__ __launch_bounds__(64) void softmax_kernel(float* __restrict__ sc) {
    float* row = sc + (size_t)blockIdx.x * TT;
    const int lane = threadIdx.x;
    float v[TT / 64];
    float mx = -1e30f;
    #pragma unroll
    for (int j = 0; j < TT / 64; ++j) {
        v[j] = row[j * 64 + lane];
        mx = fmaxf(mx, v[j]);
    }
    mx = wave_max(mx);
    float s = 0.f;
    #pragma unroll
    for (int j = 0; j < TT / 64; ++j) {
        v[j] = expf(v[j] - mx);
        s += v[j];
    }
    s = wave_sum(s);
    const float inv = 1.f / s;
    #pragma unroll
    for (int j = 0; j < TT / 64; ++j) row[j * 64 + lane] = v[j] * inv;
}

__global__ __launch_bounds__(256) void pv_kernel(const float* __restrict__ p,
                                                 const float* __restrict__ vv,
                                                 float* __restrict__ attn, int b) {
    const int t0 = blockIdx.x * 64;
    const int h = blockIdx.y;
    const int tid = threadIdx.x;
    const int i0 = (tid >> 4) << 2;  // d
    const int j0 = (tid & 15) << 2;  // t

    __shared__ float Vs[16][64];  // [s][d]
    __shared__ float Ps[16][64];  // [s][t]
    float acc[4][4] = {};
    const size_t vbase = ((size_t)b * CC + h * DKK) * TT;
    const size_t pbase = (size_t)h * TT * TT;

    for (int sc0 = 0; sc0 < TT; sc0 += 16) {
        const int r = tid >> 2;
        const int c4 = (tid & 3) << 2;
        const float* Vp = vv + vbase + (size_t)r * TT + sc0 + c4;
        const float* Pp = p + pbase + (size_t)(t0 + r) * TT + sc0 + c4;
        #pragma unroll
        for (int u = 0; u < 4; ++u) {
            Vs[c4 + u][r] = Vp[u];
            Ps[c4 + u][r] = Pp[u];
        }
        __syncthreads();
        #pragma unroll
        for (int kk = 0; kk < 16; ++kk) {
            float a[4], xv[4];
            #pragma unroll
            for (int i = 0; i < 4; ++i) a[i] = Vs[kk][i0 + i];
            #pragma unroll
            for (int j = 0; j < 4; ++j) xv[j] = Ps[kk][j0 + j];
            #pragma unroll
            for (int i = 0; i < 4; ++i)
                #pragma unroll
                for (int j = 0; j < 4; ++j)
                    acc[i][j] += a[i] * xv[j];
        }
        __syncthreads();
    }
    #pragma unroll
    for (int i = 0; i < 4; ++i) {
        float* Op = attn + vbase + (size_t)(i0 + i) * TT + t0 + j0;
        #pragma unroll
        for (int j = 0; j < 4; ++j) Op[j] = acc[i][j];
    }
}

__global__ __launch_bounds__(64) void relv_kernel(const float* __restrict__ p,
                                                  const float* __restrict__ erv,
                                                  float* __restrict__ attn, int b) {
    const int t = blockIdx.x;
    const int h = blockIdx.y;
    const int d = threadIdx.x;
    const float* prow = p + ((size_t)h * TT + t) * TT;
    float acc = 0.f;
    for (int w = 0; w < 2 * WW + 1; ++w) {
        const int s = t + w - WW;
        if (s < 0 || s >= TT) continue;
        acc += prow[s] * erv[w * DKK + d];
    }
    attn[((size_t)b * CC + h * DKK + d) * TT + t] += acc;
}

// ---------------------------------------------------------------------------
__global__ __launch_bounds__(128) void addln_kernel(float* __restrict__ x,
                                                    const float* __restrict__ y,
                                                    const float* __restrict__ g,
                                                    const float* __restrict__ bt,
                                                    const float* __restrict__ mask,
                                                    int maskY) {
    const int b = blockIdx.x / TT;
    const int t = blockIdx.x % TT;
    const float mv = maskY ? mask[b * TT + t] : 1.f;
    const int tid = threadIdx.x;
    float vals[CC / 128];
    float s = 0.f, s2 = 0.f;
    #pragma unroll
    for (int u = 0; u < CC / 128; ++u) {
        const int c = tid + u * 128;
        const size_t idx = ((size_t)b * CC + c) * TT + t;
        const float v = x[idx] + y[idx] * mv;
        vals[u] = v;
        s += v;
        s2 += v * v;
    }
    __shared__ float ws[2], ws2[2];
    const int wid = tid >> 6, lane = tid & 63;
    s = wave_sum(s);
    s2 = wave_sum(s2);
    if (lane == 0) { ws[wid] = s; ws2[wid] = s2; }
    __syncthreads();
    const float tot = ws[0] + ws[1];
    const float tot2 = ws2[0] + ws2[1];
    const float mean = tot * (1.f / CC);
    const float var = tot2 * (1.f / CC) - mean * mean;
    const float rstd = rsqrtf(var + 1e-5f);
    #pragma unroll
    for (int u = 0; u < CC / 128; ++u) {
        const int c = tid + u * 128;
        const size_t idx = ((size_t)b * CC + c) * TT + t;
        x[idx] = (vals[u] - mean) * rstd * g[c] + bt[c];
    }
}

// ---------------------------------------------------------------------------
extern "C" void kernel_launch(void* const* d_in, const int* in_sizes, int n_in,
                              void* d_out, int out_size, void* d_ws, size_t ws_size,
                              hipStream_t stream) {
    const float* x_in = (const float*)d_in[0];
    const float* mask = (const float*)d_in[1];
    const float* Wq = (const float*)d_in[2];
    const float* bq = (const float*)d_in[3];
    const float* Wk = (const float*)d_in[4];
    const float* bk = (const float*)d_in[5];
    const float* Wv = (const float*)d_in[6];
    const float* bv = (const float*)d_in[7];
    const float* Wo = (const float*)d_in[8];
    const float* bo = (const float*)d_in[9];
    const float* erk = (const float*)d_in[10];
    const float* erv = (const float*)d_in[11];
    const float* g1 = (const float*)d_in[12];
    const float* b1 = (const float*)d_in[13];
    const float* g2 = (const float*)d_in[14];
    const float* b2 = (const float*)d_in[15];
    const float* W1 = (const float*)d_in[16];
    const float* bf1 = (const float*)d_in[17];
    const float* W2 = (const float*)d_in[18];
    const float* bf2 = (const float*)d_in[19];

    // ws layout (fp32 elements), 56 MiB total:
    //   xf | qb | kb | vb | attn | sc | yb, each BCT = 2M floats (8 MiB).
    //   mid (FFN intermediate, B*F*T = 4*BCT) aliases kb..sc.
    const size_t BCT = (size_t)BB * CC * TT;  // 2,097,152
    float* xf = (float*)d_ws;
    float* qb = xf + BCT;
    float* kb = qb + BCT;
    float* vb = kb + BCT;
    float* attn = vb + BCT;
    float* sc = attn + BCT;      // per-batch scores [H,T,T] = 2M floats
    float* yb = sc + BCT;
    float* mid = kb;             // spans kb,vb,attn,sc = 4*BCT = B*F*T floats exactly

    const int eltBlocks = (int)((BCT + 255) / 256);
    init_kernel<<<eltBlocks, 256, 0, stream>>>(x_in, mask, xf);

    for (int L = 0; L < NLAYERS; ++L) {
        const float* Wq_l = Wq + (size_t)L * CC * CC;
        const float* Wk_l = Wk + (size_t)L * CC * CC;
        const float* Wv_l = Wv + (size_t)L * CC * CC;
        const float* Wo_l = Wo + (size_t)L * CC * CC;
        const float* bq_l = bq + (size_t)L * CC;
        const float* bk_l = bk + (size_t)L * CC;
        const float* bv_l = bv + (size_t)L * CC;
        const float* bo_l = bo + (size_t)L * CC;
        const float* erk_l = erk + (size_t)L * (2 * WW + 1) * DKK;
        const float* erv_l = erv + (size_t)L * (2 * WW + 1) * DKK;
        const float* g1_l = g1 + (size_t)L * CC;
        const float* b1_l = b1 + (size_t)L * CC;
        const float* g2_l = g2 + (size_t)L * CC;
        const float* b2_l = b2 + (size_t)L * CC;
        const float* W1_l = W1 + (size_t)L * FF * CC * 3;
        const float* bf1_l = bf1 + (size_t)L * FF;
        const float* W2_l = W2 + (size_t)L * CC * FF * 3;
        const float* bf2_l = bf2 + (size_t)L * CC;

        gemm_kernel<false><<<dim3(TT / 64, CC / 64, BB), 256, 0, stream>>>(
            Wq_l, bq_l, xf, qb, mask, CC, CC, 1);
        gemm_kernel<false><<<dim3(TT / 64, CC / 64, BB), 256, 0, stream>>>(
            Wk_l, bk_l, xf, kb, mask, CC, CC, 1);
        gemm_kernel<false><<<dim3(TT / 64, CC / 64, BB), 256, 0, stream>>>(
            Wv_l, bv_l, xf, vb, mask, CC, CC, 1);

        for (int b = 0; b < BB; ++b) {
            qk_kernel<<<dim3(TT / 64, TT / 64, HH), 256, 0, stream>>>(qb, kb, mask, sc, b);
            relk_kernel<<<dim3(TT, HH), 64, 0, stream>>>(qb, erk_l, mask, sc, b);
            softmax_kernel<<<HH * TT, 64, 0, stream>>>(sc);
            pv_kernel<<<dim3(TT / 64, HH), 256, 0, stream>>>(sc, vb, attn, b);
            relv_kernel<<<dim3(TT, HH), 64, 0, stream>>>(sc, erv_l, attn, b);
        }

        gemm_kernel<false><<<dim3(TT / 64, CC / 64, BB), 256, 0, stream>>>(
            Wo_l, bo_l, attn, yb, mask, CC, CC, 1);
        addln_kernel<<<BB * TT, 128, 0, stream>>>(xf, yb, g1_l, b1_l, mask, 0);

        maskmul_kernel<<<eltBlocks, 256, 0, stream>>>(xf, mask, qb);
        gemm_kernel<true><<<dim3(TT / 64, FF / 64, BB), 256, 0, stream>>>(
            W1_l, bf1_l, qb, mid, mask, FF, CC, 3);
        gemm_kernel<false><<<dim3(TT / 64, CC / 64, BB), 256, 0, stream>>>(
            W2_l, bf2_l, mid, yb, mask, CC, FF, 3);
        addln_kernel<<<BB * TT, 128, 0, stream>>>(xf, yb, g2_l, b2_l, mask, 1);
    }

    final_kernel<<<eltBlocks, 256, 0, stream>>>(xf, mask, (float*)d_out);
}

// Round 4
// 10422.823 us; speedup vs baseline: 1.4872x; 1.4872x over previous
//
#include <hip/hip_runtime.h>

// ---------------------------------------------------------------------------
// VITS-style relative-attention encoder, MI355X round 4.
// Change vs round 3 (15.5 ms, absmax 0.0156): all weight GEMMs (QKV, O-proj,
// conv1, conv2) now use bf16 MFMA (mfma_f32_16x16x32_bf16, fp32 accumulate).
// Activations transposed+converted to bf16 [B,T,C] per GEMM (k-contiguous for
// MFMA fragments). conv1 emits bf16-transposed [B,T,F] with fused ReLU*mask,
// removing the fp32 mid buffer. Attention/softmax/LN unchanged from round 3.
// ws = 60 MiB (Midt aliases qb+kb during FFN).
// ---------------------------------------------------------------------------

#define NLAYERS 6
#define BB 8
#define TT 512
#define CC 512
#define FF 2048
#define HH 8
#define DKK 64
#define WW 10

static_assert(CC == HH * DKK, "");

typedef __attribute__((ext_vector_type(8))) short short8;   // 8 bf16 = 4 VGPRs
typedef __attribute__((ext_vector_type(4))) float f32x4;

__device__ __forceinline__ unsigned short f2bs(float f) {   // fp32 -> bf16 RNE
    unsigned u = __float_as_uint(f);
    u = (u + 0x7FFFu + ((u >> 16) & 1u)) >> 16;
    return (unsigned short)u;
}

__device__ __forceinline__ float wave_sum(float v) {
    #pragma unroll
    for (int off = 32; off > 0; off >>= 1) v += __shfl_xor(v, off, 64);
    return v;
}
__device__ __forceinline__ float wave_max(float v) {
    #pragma unroll
    for (int off = 32; off > 0; off >>= 1) v = fmaxf(v, __shfl_xor(v, off, 64));
    return v;
}

// ---------------------------------------------------------------------------
__global__ __launch_bounds__(256) void init_kernel(const float* __restrict__ x,
                                                   const float* __restrict__ mask,
                                                   float* __restrict__ xf) {
    size_t i = (size_t)blockIdx.x * 256 + threadIdx.x;
    const size_t total = (size_t)BB * CC * TT;
    if (i >= total) return;
    int t = (int)(i % TT);
    int b = (int)(i / ((size_t)CC * TT));
    xf[i] = x[i] * mask[b * TT + t];
}

__global__ __launch_bounds__(256) void final_kernel(const float* __restrict__ xf,
                                                    const float* __restrict__ mask,
                                                    float* __restrict__ out) {
    size_t i = (size_t)blockIdx.x * 256 + threadIdx.x;
    const size_t total = (size_t)BB * CC * TT;
    if (i >= total) return;
    int t = (int)(i % TT);
    int b = (int)(i / ((size_t)CC * TT));
    out[i] = xf[i] * mask[b * TT + t];
}

// ---------------------------------------------------------------------------
// fp32 [B,C,T] -> bf16 [B,T,C], optional mask over t.
template <bool MASK>
__global__ __launch_bounds__(256) void trans_kernel(const float* __restrict__ in,
                                                    const float* __restrict__ mask,
                                                    unsigned short* __restrict__ out) {
    __shared__ float tile[32][33];
    const int t0 = blockIdx.x * 32;
    const int c0 = blockIdx.y * 32;
    const int b = blockIdx.z;
    const int col = threadIdx.x & 31;
    const int row = threadIdx.x >> 5;  // 0..7
    const float* src = in + ((size_t)b * CC + c0) * TT + t0;
    #pragma unroll
    for (int r = 0; r < 32; r += 8)
        tile[row + r][col] = src[(size_t)(row + r) * TT + col];   // tile[c][t]
    __syncthreads();
    unsigned short* dst = out + ((size_t)b * TT + t0) * CC + c0;
    #pragma unroll
    for (int r = 0; r < 32; r += 8) {
        const int t = row + r;
        const float m = MASK ? mask[b * TT + t0 + t] : 1.f;
        dst[(size_t)t * CC + col] = f2bs(tile[col][t] * m);
    }
}

// ---------------------------------------------------------------------------
// D[t][o] = sum_{tap,c} Xt[b][t+tap-1][c] * W[o][c*ntaps+tap]   (bf16 MFMA)
// MODE 0: Out fp32 [B,O,T] = D + bias
// MODE 1: Out bf16 [B,T,O] = relu(D + bias) * mask[t]     (conv1 -> conv2 in)
template <int MODE>
__global__ __launch_bounds__(256) void mfma_gemm(const float* __restrict__ W,
                                                 const float* __restrict__ bias,
                                                 const unsigned short* __restrict__ Xt,
                                                 void* __restrict__ Out,
                                                 const float* __restrict__ mask,
                                                 int O, int K, int ntaps) {
    const int t0 = blockIdx.x * 64;
    const int o0 = blockIdx.y * 64;
    const int b = blockIdx.z;
    const int tid = threadIdx.x;
    const int wid = tid >> 6;
    const int lane = tid & 63;
    const int ln = lane & 15;
    const int q = lane >> 4;
    const int wm = wid & 1;   // t-half of tile
    const int wn = wid >> 1;  // o-half of tile

    __shared__ unsigned short Ws[64][40];  // [o][c] pad 40 (2-way banks: free)
    __shared__ unsigned short Xs[64][40];  // [t][c]

    f32x4 acc[2][2] = {};  // [mi][ni]

    const int lda = K * ntaps;
    const unsigned short* Xb = Xt + (size_t)b * TT * K;

    const int r8 = tid >> 2;        // staging row 0..63
    const int cs = (tid & 3) << 3;  // staging col 0,8,16,24

    for (int tap = 0; tap < ntaps; ++tap) {
        const int shift = (ntaps > 1) ? (tap - 1) : 0;
        const int gt = t0 + r8 + shift;
        const bool okt = (gt >= 0) && (gt < TT);
        const unsigned short* Xrow = Xb + (size_t)(okt ? gt : 0) * K;
        for (int c0 = 0; c0 < K; c0 += 32) {
            {   // stage W tile (fp32 -> bf16)
                const float* Wp = W + (size_t)(o0 + r8) * lda + (size_t)(c0 + cs) * ntaps + tap;
                unsigned short tmp[8];
                #pragma unroll
                for (int j = 0; j < 8; ++j) tmp[j] = f2bs(Wp[(size_t)j * ntaps]);
                *(uint4*)&Ws[r8][cs] = *(const uint4*)tmp;
            }
            {   // stage X tile (already bf16, 16B load)
                uint4 v = make_uint4(0u, 0u, 0u, 0u);
                if (okt) v = *(const uint4*)(Xrow + c0 + cs);
                *(uint4*)&Xs[r8][cs] = v;
            }
            __syncthreads();
            short8 afr[2], bfr[2];
            #pragma unroll
            for (int mi = 0; mi < 2; ++mi)
                afr[mi] = *(const short8*)&Xs[wm * 32 + mi * 16 + ln][q * 8];
            #pragma unroll
            for (int ni = 0; ni < 2; ++ni)
                bfr[ni] = *(const short8*)&Ws[wn * 32 + ni * 16 + ln][q * 8];
            #pragma unroll
            for (int mi = 0; mi < 2; ++mi)
                #pragma unroll
                for (int ni = 0; ni < 2; ++ni)
                    acc[mi][ni] = __builtin_amdgcn_mfma_f32_16x16x32_bf16(
                        afr[mi], bfr[ni], acc[mi][ni], 0, 0, 0);
            __syncthreads();
        }
    }

    #pragma unroll
    for (int ni = 0; ni < 2; ++ni) {
        const int o = o0 + wn * 32 + ni * 16 + ln;
        const float bv = bias[o];
        #pragma unroll
        for (int mi = 0; mi < 2; ++mi) {
            const int tb = t0 + wm * 32 + mi * 16 + q * 4;  // 4 consecutive t
            if (MODE == 0) {
                f32x4 v;
                #pragma unroll
                for (int r = 0; r < 4; ++r) v[r] = acc[mi][ni][r] + bv;
                *(f32x4*)((float*)Out + ((size_t)b * O + o) * TT + tb) = v;
            } else {
                unsigned short* Op = (unsigned short*)Out;
                #pragma unroll
                for (int r = 0; r < 4; ++r) {
                    float v = acc[mi][ni][r] + bv;
                    v = fmaxf(v, 0.f) * mask[b * TT + tb + r];
                    Op[((size_t)b * TT + tb + r) * (size_t)O + o] = f2bs(v);
                }
            }
        }
    }
}

// ---------------------------------------------------------------------------
// Per-batch attention (round-3 kernels, fp32). sc is [H,T,T] for batch b.
__global__ __launch_bounds__(256) void qk_kernel(const float* __restrict__ qv,
                                                 const float* __restrict__ kv,
                                                 const float* __restrict__ mask,
                                                 float* __restrict__ sc, int b) {
    const int s0 = blockIdx.x * 64;
    const int t0 = blockIdx.y * 64;
    const int h = blockIdx.z;
    const int tid = threadIdx.x;
    const int i0 = (tid >> 4) << 2;
    const int j0 = (tid & 15) << 2;

    __shared__ float Qs[16][64];
    __shared__ float Ks[16][64];
    float acc[4][4] = {};
    const size_t base = ((size_t)b * CC + h * DKK) * TT;

    for (int cc = 0; cc < DKK; cc += 16) {
        const int jr = tid >> 4;
        const int c4 = (tid & 15) << 2;
        const float* Qp = qv + base + (size_t)(cc + jr) * TT + t0 + c4;
        const float* Kp = kv + base + (size_t)(cc + jr) * TT + s0 + c4;
        #pragma unroll
        for (int u = 0; u < 4; ++u) {
            Qs[jr][c4 + u] = Qp[u];
            Ks[jr][c4 + u] = Kp[u];
        }
        __syncthreads();
        #pragma unroll
        for (int kk = 0; kk < 16; ++kk) {
            float a[4], bb_[4];
            #pragma unroll
            for (int i = 0; i < 4; ++i) a[i] = Qs[kk][i0 + i];
            #pragma unroll
            for (int j = 0; j < 4; ++j) bb_[j] = Ks[kk][j0 + j];
            #pragma unroll
            for (int i = 0; i < 4; ++i)
                #pragma unroll
                for (int j = 0; j < 4; ++j)
                    acc[i][j] += a[i] * bb_[j];
        }
        __syncthreads();
    }

    #pragma unroll
    for (int i = 0; i < 4; ++i) {
        const int t = t0 + i0 + i;
        const float mt = mask[b * TT + t];
        float* row = sc + ((size_t)h * TT + t) * TT + s0 + j0;
        #pragma unroll
        for (int j = 0; j < 4; ++j) {
            const float ms = mask[b * TT + s0 + j0 + j];
            row[j] = (mt * ms == 0.f) ? -1e4f : 0.125f * acc[i][j];
        }
    }
}

__global__ __launch_bounds__(64) void relk_kernel(const float* __restrict__ qv,
                                                  const float* __restrict__ erk,
                                                  const float* __restrict__ mask,
                                                  float* __restrict__ sc, int b) {
    const int t = blockIdx.x;
    const int h = blockIdx.y;
    const int d = threadIdx.x;
    const float mt = mask[b * TT + t];
    const float q0 = qv[((size_t)b * CC + h * DKK + d) * TT + t];
    float* row = sc + ((size_t)h * TT + t) * TT;
    for (int w = 0; w < 2 * WW + 1; ++w) {
        const int s = t + w - WW;
        if (s < 0 || s >= TT) continue;
        const float part = q0 * erk[w * DKK + d];
        const float sum = wave_sum(part);
        if (d == 0) {
            const float ms = mask[b * TT + s];
            if (mt * ms != 0.f) row[s] += 0.125f * sum;
        }
    }
}

__global__ __launch_bounds__(64) void softmax_kernel(float* __restrict__ sc) {
    float* row = sc + (size_t)blockIdx.x * TT;
    const int lane = threadIdx.x;
    float v[TT / 64];
    float mx = -1e30f;
    #pragma unroll
    for (int j = 0; j < TT / 64; ++j) {
        v[j] = row[j * 64 + lane];
        mx = fmaxf(mx, v[j]);
    }
    mx = wave_max(mx);
    float s = 0.f;
    #pragma unroll
    for (int j = 0; j < TT / 64; ++j) {
        v[j] = expf(v[j] - mx);
        s += v[j];
    }
    s = wave_sum(s);
    const float inv = 1.f / s;
    #pragma unroll
    for (int j = 0; j < TT / 64; ++j) row[j * 64 + lane] = v[j] * inv;
}

__global__ __launch_bounds__(256) void pv_kernel(const float* __restrict__ p,
                                                 const float* __restrict__ vv,
                                                 float* __restrict__ attn, int b) {
    const int t0 = blockIdx.x * 64;
    const int h = blockIdx.y;
    const int tid = threadIdx.x;
    const int i0 = (tid >> 4) << 2;
    const int j0 = (tid & 15) << 2;

    __shared__ float Vs[16][64];
    __shared__ float Ps[16][64];
    float acc[4][4] = {};
    const size_t vbase = ((size_t)b * CC + h * DKK) * TT;
    const size_t pbase = (size_t)h * TT * TT;

    for (int sc0 = 0; sc0 < TT; sc0 += 16) {
        const int r = tid >> 2;
        const int c4 = (tid & 3) << 2;
        const float* Vp = vv + vbase + (size_t)r * TT + sc0 + c4;
        const float* Pp = p + pbase + (size_t)(t0 + r) * TT + sc0 + c4;
        #pragma unroll
        for (int u = 0; u < 4; ++u) {
            Vs[c4 + u][r] = Vp[u];
            Ps[c4 + u][r] = Pp[u];
        }
        __syncthreads();
        #pragma unroll
        for (int kk = 0; kk < 16; ++kk) {
            float a[4], xv[4];
            #pragma unroll
            for (int i = 0; i < 4; ++i) a[i] = Vs[kk][i0 + i];
            #pragma unroll
            for (int j = 0; j < 4; ++j) xv[j] = Ps[kk][j0 + j];
            #pragma unroll
            for (int i = 0; i < 4; ++i)
                #pragma unroll
                for (int j = 0; j < 4; ++j)
                    acc[i][j] += a[i] * xv[j];
        }
        __syncthreads();
    }
    #pragma unroll
    for (int i = 0; i < 4; ++i) {
        float* Op = attn + vbase + (size_t)(i0 + i) * TT + t0 + j0;
        #pragma unroll
        for (int j = 0; j < 4; ++j) Op[j] = acc[i][j];
    }
}

__global__ __launch_bounds__(64) void relv_kernel(const float* __restrict__ p,
                                                  const float* __restrict__ erv,
                                                  float* __restrict__ attn, int b) {
    const int t = blockIdx.x;
    const int h = blockIdx.y;
    const int d = threadIdx.x;
    const float* prow = p + ((size_t)h * TT + t) * TT;
    float acc = 0.f;
    for (int w = 0; w < 2 * WW + 1; ++w) {
        const int s = t + w - WW;
        if (s < 0 || s >= TT) continue;
        acc += prow[s] * erv[w * DKK + d];
    }
    attn[((size_t)b * CC + h * DKK + d) * TT + t] += acc;
}

// ---------------------------------------------------------------------------
__global__ __launch_bounds__(128) void addln_kernel(float* __restrict__ x,
                                                    const float* __restrict__ y,
                                                    const float* __restrict__ g,
                                                    const float* __restrict__ bt,
                                                    const float* __restrict__ mask,
                                                    int maskY) {
    const int b = blockIdx.x / TT;
    const int t = blockIdx.x % TT;
    const float mv = maskY ? mask[b * TT + t] : 1.f;
    const int tid = threadIdx.x;
    float vals[CC / 128];
    float s = 0.f, s2 = 0.f;
    #pragma unroll
    for (int u = 0; u < CC / 128; ++u) {
        const int c = tid + u * 128;
        const size_t idx = ((size_t)b * CC + c) * TT + t;
        const float v = x[idx] + y[idx] * mv;
        vals[u] = v;
        s += v;
        s2 += v * v;
    }
    __shared__ float ws[2], ws2[2];
    const int wid = tid >> 6, lane = tid & 63;
    s = wave_sum(s);
    s2 = wave_sum(s2);
    if (lane == 0) { ws[wid] = s; ws2[wid] = s2; }
    __syncthreads();
    const float tot = ws[0] + ws[1];
    const float tot2 = ws2[0] + ws2[1];
    const float mean = tot * (1.f / CC);
    const float var = tot2 * (1.f / CC) - mean * mean;
    const float rstd = rsqrtf(var + 1e-5f);
    #pragma unroll
    for (int u = 0; u < CC / 128; ++u) {
        const int c = tid + u * 128;
        const size_t idx = ((size_t)b * CC + c) * TT + t;
        x[idx] = (vals[u] - mean) * rstd * g[c] + bt[c];
    }
}

// ---------------------------------------------------------------------------
extern "C" void kernel_launch(void* const* d_in, const int* in_sizes, int n_in,
                              void* d_out, int out_size, void* d_ws, size_t ws_size,
                              hipStream_t stream) {
    const float* x_in = (const float*)d_in[0];
    const float* mask = (const float*)d_in[1];
    const float* Wq = (const float*)d_in[2];
    const float* bq = (const float*)d_in[3];
    const float* Wk = (const float*)d_in[4];
    const float* bk = (const float*)d_in[5];
    const float* Wv = (const float*)d_in[6];
    const float* bv = (const float*)d_in[7];
    const float* Wo = (const float*)d_in[8];
    const float* bo = (const float*)d_in[9];
    const float* erk = (const float*)d_in[10];
    const float* erv = (const float*)d_in[11];
    const float* g1 = (const float*)d_in[12];
    const float* b1 = (const float*)d_in[13];
    const float* g2 = (const float*)d_in[14];
    const float* b2 = (const float*)d_in[15];
    const float* W1 = (const float*)d_in[16];
    const float* bf1 = (const float*)d_in[17];
    const float* W2 = (const float*)d_in[18];
    const float* bf2 = (const float*)d_in[19];

    // ws layout (MiB): xf 0-8 | Xt 8-12 (bf16 [B,T,C]) | qb 12-20 | kb 20-28 |
    // vb 28-36 | attn 36-44 | sc 44-52 | yb 52-60.  Midt (bf16 [B,T,F], 16 MiB)
    // aliases qb+kb (12-28) during the FFN (both dead there). Total 60 MiB.
    const size_t BCT = (size_t)BB * CC * TT;  // 2,097,152
    float* xf = (float*)d_ws;
    unsigned short* Xt = (unsigned short*)(xf + BCT);           // 4 MiB
    float* qb = (float*)(Xt + BCT);
    float* kb = qb + BCT;
    float* vb = kb + BCT;
    float* attn = vb + BCT;
    float* sc = attn + BCT;
    float* yb = sc + BCT;
    unsigned short* Midt = (unsigned short*)qb;                 // [B,T,F] bf16

    const int eltBlocks = (int)((BCT + 255) / 256);
    init_kernel<<<eltBlocks, 256, 0, stream>>>(x_in, mask, xf);

    const dim3 trGrid(TT / 32, CC / 32, BB);
    const dim3 gProj(TT / 64, CC / 64, BB);   // QKV / O / conv2
    const dim3 gConv1(TT / 64, FF / 64, BB);

    for (int L = 0; L < NLAYERS; ++L) {
        const float* Wq_l = Wq + (size_t)L * CC * CC;
        const float* Wk_l = Wk + (size_t)L * CC * CC;
        const float* Wv_l = Wv + (size_t)L * CC * CC;
        const float* Wo_l = Wo + (size_t)L * CC * CC;
        const float* bq_l = bq + (size_t)L * CC;
        const float* bk_l = bk + (size_t)L * CC;
        const float* bv_l = bv + (size_t)L * CC;
        const float* bo_l = bo + (size_t)L * CC;
        const float* erk_l = erk + (size_t)L * (2 * WW + 1) * DKK;
        const float* erv_l = erv + (size_t)L * (2 * WW + 1) * DKK;
        const float* g1_l = g1 + (size_t)L * CC;
        const float* b1_l = b1 + (size_t)L * CC;
        const float* g2_l = g2 + (size_t)L * CC;
        const float* b2_l = b2 + (size_t)L * CC;
        const float* W1_l = W1 + (size_t)L * FF * CC * 3;
        const float* bf1_l = bf1 + (size_t)L * FF;
        const float* W2_l = W2 + (size_t)L * CC * FF * 3;
        const float* bf2_l = bf2 + (size_t)L * CC;

        // QKV projections (bf16 MFMA)
        trans_kernel<false><<<trGrid, 256, 0, stream>>>(xf, mask, Xt);
        mfma_gemm<0><<<gProj, 256, 0, stream>>>(Wq_l, bq_l, Xt, qb, mask, CC, CC, 1);
        mfma_gemm<0><<<gProj, 256, 0, stream>>>(Wk_l, bk_l, Xt, kb, mask, CC, CC, 1);
        mfma_gemm<0><<<gProj, 256, 0, stream>>>(Wv_l, bv_l, Xt, vb, mask, CC, CC, 1);

        // attention (per-batch fp32, round-3 structure)
        for (int b = 0; b < BB; ++b) {
            qk_kernel<<<dim3(TT / 64, TT / 64, HH), 256, 0, stream>>>(qb, kb, mask, sc, b);
            relk_kernel<<<dim3(TT, HH), 64, 0, stream>>>(qb, erk_l, mask, sc, b);
            softmax_kernel<<<HH * TT, 64, 0, stream>>>(sc);
            pv_kernel<<<dim3(TT / 64, HH), 256, 0, stream>>>(sc, vb, attn, b);
            relv_kernel<<<dim3(TT, HH), 64, 0, stream>>>(sc, erv_l, attn, b);
        }

        // O-projection + residual LN
        trans_kernel<false><<<trGrid, 256, 0, stream>>>(attn, mask, Xt);
        mfma_gemm<0><<<gProj, 256, 0, stream>>>(Wo_l, bo_l, Xt, yb, mask, CC, CC, 1);
        addln_kernel<<<BB * TT, 128, 0, stream>>>(xf, yb, g1_l, b1_l, mask, 0);

        // FFN: masked transpose -> conv1 (ReLU*mask, bf16-T out) -> conv2 -> LN
        trans_kernel<true><<<trGrid, 256, 0, stream>>>(xf, mask, Xt);
        mfma_gemm<1><<<gConv1, 256, 0, stream>>>(W1_l, bf1_l, Xt, Midt, mask, FF, CC, 3);
        mfma_gemm<0><<<gProj, 256, 0, stream>>>(W2_l, bf2_l, Midt, yb, mask, CC, FF, 3);
        addln_kernel<<<BB * TT, 128, 0, stream>>>(xf, yb, g2_l, b2_l, mask, 1);
    }

    final_kernel<<<eltBlocks, 256, 0, stream>>>(xf, mask, (float*)d_out);
}

// Round 5
// 7665.314 us; speedup vs baseline: 2.0222x; 1.3597x over previous
//
#include <hip/hip_runtime.h>

// ---------------------------------------------------------------------------
// VITS-style relative-attention encoder, MI355X round 5.
// Change vs round 4 (10.4 ms): the entire attention (QK^T + banded rel-K +
// mask + softmax + PV + banded rel-V) is fused into ONE flash-style MFMA
// kernel per layer (online softmax, P round-trips through LDS to convert
// C-layout -> A-layout). Removes 40 launches/layer and the scores buffer.
// Weight GEMMs unchanged from round 4 (bf16 MFMA, verified).
// ---------------------------------------------------------------------------

#define NLAYERS 6
#define BB 8
#define TT 512
#define CC 512
#define FF 2048
#define HH 8
#define DKK 64
#define WW 10

static_assert(CC == HH * DKK, "");

typedef __attribute__((ext_vector_type(8))) short short8;   // 8 bf16 = 4 VGPRs
typedef __attribute__((ext_vector_type(4))) float f32x4;

__device__ __forceinline__ unsigned short f2bs(float f) {   // fp32 -> bf16 RNE
    unsigned u = __float_as_uint(f);
    u = (u + 0x7FFFu + ((u >> 16) & 1u)) >> 16;
    return (unsigned short)u;
}
__device__ __forceinline__ float bf2f(unsigned short u) {
    return __uint_as_float(((unsigned)u) << 16);
}

__device__ __forceinline__ float wave_sum(float v) {
    #pragma unroll
    for (int off = 32; off > 0; off >>= 1) v += __shfl_xor(v, off, 64);
    return v;
}

// ---------------------------------------------------------------------------
__global__ __launch_bounds__(256) void init_kernel(const float* __restrict__ x,
                                                   const float* __restrict__ mask,
                                                   float* __restrict__ xf) {
    size_t i = (size_t)blockIdx.x * 256 + threadIdx.x;
    const size_t total = (size_t)BB * CC * TT;
    if (i >= total) return;
    int t = (int)(i % TT);
    int b = (int)(i / ((size_t)CC * TT));
    xf[i] = x[i] * mask[b * TT + t];
}

__global__ __launch_bounds__(256) void final_kernel(const float* __restrict__ xf,
                                                    const float* __restrict__ mask,
                                                    float* __restrict__ out) {
    size_t i = (size_t)blockIdx.x * 256 + threadIdx.x;
    const size_t total = (size_t)BB * CC * TT;
    if (i >= total) return;
    int t = (int)(i % TT);
    int b = (int)(i / ((size_t)CC * TT));
    out[i] = xf[i] * mask[b * TT + t];
}

// ---------------------------------------------------------------------------
// fp32 [B,C,T] -> bf16 [B,T,C], optional mask over t.
template <bool MASK>
__global__ __launch_bounds__(256) void trans_kernel(const float* __restrict__ in,
                                                    const float* __restrict__ mask,
                                                    unsigned short* __restrict__ out) {
    __shared__ float tile[32][33];
    const int t0 = blockIdx.x * 32;
    const int c0 = blockIdx.y * 32;
    const int b = blockIdx.z;
    const int col = threadIdx.x & 31;
    const int row = threadIdx.x >> 5;  // 0..7
    const float* src = in + ((size_t)b * CC + c0) * TT + t0;
    #pragma unroll
    for (int r = 0; r < 32; r += 8)
        tile[row + r][col] = src[(size_t)(row + r) * TT + col];   // tile[c][t]
    __syncthreads();
    unsigned short* dst = out + ((size_t)b * TT + t0) * CC + c0;
    #pragma unroll
    for (int r = 0; r < 32; r += 8) {
        const int t = row + r;
        const float m = MASK ? mask[b * TT + t0 + t] : 1.f;
        dst[(size_t)t * CC + col] = f2bs(tile[col][t] * m);
    }
}

// ---------------------------------------------------------------------------
// D[t][o] = sum_{tap,c} Xt[b][t+tap-1][c] * W[o][c*ntaps+tap]   (bf16 MFMA)
// MODE 0: Out fp32 [B,O,T] = D + bias
// MODE 1: Out bf16 [B,T,O] = relu(D + bias) * mask[t]
template <int MODE>
__global__ __launch_bounds__(256) void mfma_gemm(const float* __restrict__ W,
                                                 const float* __restrict__ bias,
                                                 const unsigned short* __restrict__ Xt,
                                                 void* __restrict__ Out,
                                                 const float* __restrict__ mask,
                                                 int O, int K, int ntaps) {
    const int t0 = blockIdx.x * 64;
    const int o0 = blockIdx.y * 64;
    const int b = blockIdx.z;
    const int tid = threadIdx.x;
    const int wid = tid >> 6;
    const int lane = tid & 63;
    const int ln = lane & 15;
    const int q = lane >> 4;
    const int wm = wid & 1;
    const int wn = wid >> 1;

    __shared__ unsigned short Ws[64][40];
    __shared__ unsigned short Xs[64][40];

    f32x4 acc[2][2] = {};

    const int lda = K * ntaps;
    const unsigned short* Xb = Xt + (size_t)b * TT * K;

    const int r8 = tid >> 2;
    const int cs = (tid & 3) << 3;

    for (int tap = 0; tap < ntaps; ++tap) {
        const int shift = (ntaps > 1) ? (tap - 1) : 0;
        const int gt = t0 + r8 + shift;
        const bool okt = (gt >= 0) && (gt < TT);
        const unsigned short* Xrow = Xb + (size_t)(okt ? gt : 0) * K;
        for (int c0 = 0; c0 < K; c0 += 32) {
            {
                const float* Wp = W + (size_t)(o0 + r8) * lda + (size_t)(c0 + cs) * ntaps + tap;
                unsigned short tmp[8];
                #pragma unroll
                for (int j = 0; j < 8; ++j) tmp[j] = f2bs(Wp[(size_t)j * ntaps]);
                *(uint4*)&Ws[r8][cs] = *(const uint4*)tmp;
            }
            {
                uint4 v = make_uint4(0u, 0u, 0u, 0u);
                if (okt) v = *(const uint4*)(Xrow + c0 + cs);
                *(uint4*)&Xs[r8][cs] = v;
            }
            __syncthreads();
            short8 afr[2], bfr[2];
            #pragma unroll
            for (int mi = 0; mi < 2; ++mi)
                afr[mi] = *(const short8*)&Xs[wm * 32 + mi * 16 + ln][q * 8];
            #pragma unroll
            for (int ni = 0; ni < 2; ++ni)
                bfr[ni] = *(const short8*)&Ws[wn * 32 + ni * 16 + ln][q * 8];
            #pragma unroll
            for (int mi = 0; mi < 2; ++mi)
                #pragma unroll
                for (int ni = 0; ni < 2; ++ni)
                    acc[mi][ni] = __builtin_amdgcn_mfma_f32_16x16x32_bf16(
                        afr[mi], bfr[ni], acc[mi][ni], 0, 0, 0);
            __syncthreads();
        }
    }

    #pragma unroll
    for (int ni = 0; ni < 2; ++ni) {
        const int o = o0 + wn * 32 + ni * 16 + ln;
        const float bv = bias[o];
        #pragma unroll
        for (int mi = 0; mi < 2; ++mi) {
            const int tb = t0 + wm * 32 + mi * 16 + q * 4;
            if (MODE == 0) {
                f32x4 v;
                #pragma unroll
                for (int r = 0; r < 4; ++r) v[r] = acc[mi][ni][r] + bv;
                *(f32x4*)((float*)Out + ((size_t)b * O + o) * TT + tb) = v;
            } else {
                unsigned short* Op = (unsigned short*)Out;
                #pragma unroll
                for (int r = 0; r < 4; ++r) {
                    float v = acc[mi][ni][r] + bv;
                    v = fmaxf(v, 0.f) * mask[b * TT + tb + r];
                    Op[((size_t)b * TT + tb + r) * (size_t)O + o] = f2bs(v);
                }
            }
        }
    }
}

// ---------------------------------------------------------------------------
// Fused relative-position attention (flash-style, bf16 MFMA, online softmax).
// Block = (t-tile of 64) x (b,h). Never materializes scores.
// Handles: S = (q/8)K^T + banded relK, mask -> -1e4, softmax, O = P V + relV.
__global__ __launch_bounds__(256) void fattn_kernel(const float* __restrict__ qg,
                                                    const float* __restrict__ kg,
                                                    const float* __restrict__ vg,
                                                    const float* __restrict__ mask,
                                                    const float* __restrict__ erk,
                                                    const float* __restrict__ erv,
                                                    float* __restrict__ attn) {
    const int t0 = blockIdx.x * 64;
    const int bh = blockIdx.y;
    const int b = bh >> 3, h = bh & 7;
    const int tid = threadIdx.x;
    const int wm = tid >> 6;          // wave owns t rows [wm*16, wm*16+16)
    const int lane = tid & 63;
    const int ln = lane & 15;
    const int q4 = lane >> 4;

    __shared__ unsigned short Qs[64][72];  // [t][d]  (pre-scaled by 1/8)
    __shared__ unsigned short Ks[64][72];  // [s][d]
    __shared__ unsigned short Vs[64][72];  // [d][s]
    __shared__ unsigned short Ps[64][72];  // [t][s]
    __shared__ float rel[64][2 * WW + 1];  // banded relK logits (scaled)
    __shared__ float ervs[2 * WW + 1][DKK];
    __shared__ float mtile[64];
    __shared__ float mstile[64];

    const size_t base = ((size_t)b * CC + h * DKK) * TT;

    // ---- stage Q (transpose [d][t] -> [t][d], * 1/8), mask row, ervs ----
    {
        const int d = tid >> 2;
        const int tg = (tid & 3) << 4;
        const float* Qp = qg + base + (size_t)d * TT + t0 + tg;
        #pragma unroll
        for (int i = 0; i < 16; i += 4) {
            f32x4 v = *(const f32x4*)(Qp + i);
            #pragma unroll
            for (int u = 0; u < 4; ++u)
                Qs[tg + i + u][d] = f2bs(v[u] * 0.125f);
        }
    }
    if (tid < 64) mtile[tid] = mask[b * TT + t0 + tid];
    for (int idx = tid; idx < (2 * WW + 1) * DKK; idx += 256)
        ervs[idx / DKK][idx % DKK] = erv[idx];
    __syncthreads();

    // ---- banded relK logits: rel[t][w] = sum_d Qs[t][d] * erk[w][d] ----
    for (int idx = tid; idx < 64 * (2 * WW + 1); idx += 256) {
        const int t = idx / (2 * WW + 1), w = idx % (2 * WW + 1);
        float s = 0.f;
        for (int d = 0; d < DKK; ++d)
            s += bf2f(Qs[t][d]) * erk[w * DKK + d];
        rel[t][w] = s;
    }
    __syncthreads();

    // ---- online-softmax state ----
    float m_run[4], l_run[4];
    #pragma unroll
    for (int r = 0; r < 4; ++r) { m_run[r] = -1e30f; l_run[r] = 0.f; }
    f32x4 Oacc[4] = {};  // [ni]: d = ni*16+ln, t = wm*16+q4*4+r
    f32x4 Racc[4] = {};

    for (int s0 = 0; s0 < TT; s0 += 64) {
        // stage K (transpose) + V (direct) + mask col
        {
            const int d = tid >> 2;
            const int sg = (tid & 3) << 4;
            const float* Kp = kg + base + (size_t)d * TT + s0 + sg;
            const float* Vp = vg + base + (size_t)d * TT + s0 + sg;
            unsigned short tmpv[16];
            #pragma unroll
            for (int i = 0; i < 16; i += 4) {
                f32x4 kv = *(const f32x4*)(Kp + i);
                f32x4 vv = *(const f32x4*)(Vp + i);
                #pragma unroll
                for (int u = 0; u < 4; ++u) {
                    Ks[sg + i + u][d] = f2bs(kv[u]);
                    tmpv[i + u] = f2bs(vv[u]);
                }
            }
            *(uint4*)&Vs[d][sg] = *(const uint4*)tmpv;
            *(uint4*)&Vs[d][sg + 8] = *(const uint4*)(tmpv + 8);
        }
        if (tid < 64) mstile[tid] = mask[b * TT + s0 + tid];
        __syncthreads();

        // QK^T (m=t, n=s), K=64 via two chained K=32 MFMAs
        f32x4 accs[4] = {};
        {
            short8 a0 = *(const short8*)&Qs[wm * 16 + ln][q4 * 8];
            short8 a1 = *(const short8*)&Qs[wm * 16 + ln][32 + q4 * 8];
            #pragma unroll
            for (int ni = 0; ni < 4; ++ni) {
                short8 b0 = *(const short8*)&Ks[ni * 16 + ln][q4 * 8];
                short8 b1 = *(const short8*)&Ks[ni * 16 + ln][32 + q4 * 8];
                accs[ni] = __builtin_amdgcn_mfma_f32_16x16x32_bf16(a0, b0, accs[ni], 0, 0, 0);
                accs[ni] = __builtin_amdgcn_mfma_f32_16x16x32_bf16(a1, b1, accs[ni], 0, 0, 0);
            }
        }

        // band add + mask + row max (reduce over 16-lane group)
        float mx[4];
        #pragma unroll
        for (int r = 0; r < 4; ++r) {
            const int tl = wm * 16 + q4 * 4 + r;
            const float mt = mtile[tl];
            float best = -1e30f;
            #pragma unroll
            for (int ni = 0; ni < 4; ++ni) {
                const int sl = ni * 16 + ln;
                const int wb = (s0 + sl) - (t0 + tl) + WW;
                float v = accs[ni][r];
                if ((unsigned)wb <= 2u * WW) v += rel[tl][wb];
                if (mt * mstile[sl] == 0.f) v = -1e4f;
                accs[ni][r] = v;
                best = fmaxf(best, v);
            }
            #pragma unroll
            for (int off = 8; off >= 1; off >>= 1)
                best = fmaxf(best, __shfl_xor(best, off, 64));
            mx[r] = best;
        }

        // online softmax update
        #pragma unroll
        for (int r = 0; r < 4; ++r) {
            const float mnew = fmaxf(m_run[r], mx[r]);
            const float alpha = __expf(m_run[r] - mnew);
            m_run[r] = mnew;
            float rsum = 0.f;
            #pragma unroll
            for (int ni = 0; ni < 4; ++ni) {
                const float p = __expf(accs[ni][r] - mnew);
                accs[ni][r] = p;
                rsum += p;
            }
            #pragma unroll
            for (int off = 8; off >= 1; off >>= 1)
                rsum += __shfl_xor(rsum, off, 64);
            l_run[r] = l_run[r] * alpha + rsum;
            #pragma unroll
            for (int ni = 0; ni < 4; ++ni) {
                Oacc[ni][r] *= alpha;
                Racc[ni][r] *= alpha;
            }
        }

        // P: C-layout -> LDS (A-layout round-trip per guide §5)
        #pragma unroll
        for (int ni = 0; ni < 4; ++ni)
            #pragma unroll
            for (int r = 0; r < 4; ++r)
                Ps[wm * 16 + q4 * 4 + r][ni * 16 + ln] = f2bs(accs[ni][r]);
        __syncthreads();

        // PV: O[t][d] += P[t][s] V[d][s]
        {
            short8 a0 = *(const short8*)&Ps[wm * 16 + ln][q4 * 8];
            short8 a1 = *(const short8*)&Ps[wm * 16 + ln][32 + q4 * 8];
            #pragma unroll
            for (int ni = 0; ni < 4; ++ni) {
                short8 b0 = *(const short8*)&Vs[ni * 16 + ln][q4 * 8];
                short8 b1 = *(const short8*)&Vs[ni * 16 + ln][32 + q4 * 8];
                Oacc[ni] = __builtin_amdgcn_mfma_f32_16x16x32_bf16(a0, b0, Oacc[ni], 0, 0, 0);
                Oacc[ni] = __builtin_amdgcn_mfma_f32_16x16x32_bf16(a1, b1, Oacc[ni], 0, 0, 0);
            }
        }

        // banded relV: Racc[t][d] += sum_{s in band & tile} P(t,s) erv[s-t+W][d]
        if (s0 + 63 >= t0 - WW && s0 <= t0 + 63 + WW) {
            #pragma unroll
            for (int r = 0; r < 4; ++r) {
                const int tl = wm * 16 + q4 * 4 + r;
                const int tg = t0 + tl;
                for (int w = 0; w <= 2 * WW; ++w) {
                    const int sl = tg + w - WW - s0;
                    if ((unsigned)sl < 64u) {
                        const float p = bf2f(Ps[tl][sl]);
                        #pragma unroll
                        for (int ni = 0; ni < 4; ++ni)
                            Racc[ni][r] += p * ervs[w][ni * 16 + ln];
                    }
                }
            }
        }
        __syncthreads();
    }

    // epilogue: attn[b, h*64+d, t] = (O + R) / l
    #pragma unroll
    for (int ni = 0; ni < 4; ++ni) {
        const int d = ni * 16 + ln;
        f32x4 o;
        #pragma unroll
        for (int r = 0; r < 4; ++r)
            o[r] = (Oacc[ni][r] + Racc[ni][r]) / l_run[r];
        *(f32x4*)(attn + base + (size_t)d * TT + t0 + wm * 16 + q4 * 4) = o;
    }
}

// ---------------------------------------------------------------------------
__global__ __launch_bounds__(128) void addln_kernel(float* __restrict__ x,
                                                    const float* __restrict__ y,
                                                    const float* __restrict__ g,
                                                    const float* __restrict__ bt,
                                                    const float* __restrict__ mask,
                                                    int maskY) {
    const int b = blockIdx.x / TT;
    const int t = blockIdx.x % TT;
    const float mv = maskY ? mask[b * TT + t] : 1.f;
    const int tid = threadIdx.x;
    float vals[CC / 128];
    float s = 0.f, s2 = 0.f;
    #pragma unroll
    for (int u = 0; u < CC / 128; ++u) {
        const int c = tid + u * 128;
        const size_t idx = ((size_t)b * CC + c) * TT + t;
        const float v = x[idx] + y[idx] * mv;
        vals[u] = v;
        s += v;
        s2 += v * v;
    }
    __shared__ float ws[2], ws2[2];
    const int wid = tid >> 6, lane = tid & 63;
    s = wave_sum(s);
    s2 = wave_sum(s2);
    if (lane == 0) { ws[wid] = s; ws2[wid] = s2; }
    __syncthreads();
    const float tot = ws[0] + ws[1];
    const float tot2 = ws2[0] + ws2[1];
    const float mean = tot * (1.f / CC);
    const float var = tot2 * (1.f / CC) - mean * mean;
    const float rstd = rsqrtf(var + 1e-5f);
    #pragma unroll
    for (int u = 0; u < CC / 128; ++u) {
        const int c = tid + u * 128;
        const size_t idx = ((size_t)b * CC + c) * TT + t;
        x[idx] = (vals[u] - mean) * rstd * g[c] + bt[c];
    }
}

// ---------------------------------------------------------------------------
extern "C" void kernel_launch(void* const* d_in, const int* in_sizes, int n_in,
                              void* d_out, int out_size, void* d_ws, size_t ws_size,
                              hipStream_t stream) {
    const float* x_in = (const float*)d_in[0];
    const float* mask = (const float*)d_in[1];
    const float* Wq = (const float*)d_in[2];
    const float* bq = (const float*)d_in[3];
    const float* Wk = (const float*)d_in[4];
    const float* bk = (const float*)d_in[5];
    const float* Wv = (const float*)d_in[6];
    const float* bv = (const float*)d_in[7];
    const float* Wo = (const float*)d_in[8];
    const float* bo = (const float*)d_in[9];
    const float* erk = (const float*)d_in[10];
    const float* erv = (const float*)d_in[11];
    const float* g1 = (const float*)d_in[12];
    const float* b1 = (const float*)d_in[13];
    const float* g2 = (const float*)d_in[14];
    const float* b2 = (const float*)d_in[15];
    const float* W1 = (const float*)d_in[16];
    const float* bf1 = (const float*)d_in[17];
    const float* W2 = (const float*)d_in[18];
    const float* bf2 = (const float*)d_in[19];

    // ws layout (MiB): xf 0-8 | Xt 8-12 (bf16 [B,T,C]) | qb 12-20 | kb 20-28 |
    // vb 28-36 | attn 36-44 | yb 44-52.  Midt (bf16 [B,T,F], 16 MiB) aliases
    // qb+kb during the FFN. Total 52 MiB.
    const size_t BCT = (size_t)BB * CC * TT;  // 2,097,152
    float* xf = (float*)d_ws;
    unsigned short* Xt = (unsigned short*)(xf + BCT);
    float* qb = (float*)(Xt + BCT);
    float* kb = qb + BCT;
    float* vb = kb + BCT;
    float* attn = vb + BCT;
    float* yb = attn + BCT;
    unsigned short* Midt = (unsigned short*)qb;

    const int eltBlocks = (int)((BCT + 255) / 256);
    init_kernel<<<eltBlocks, 256, 0, stream>>>(x_in, mask, xf);

    const dim3 trGrid(TT / 32, CC / 32, BB);
    const dim3 gProj(TT / 64, CC / 64, BB);
    const dim3 gConv1(TT / 64, FF / 64, BB);
    const dim3 gAttn(TT / 64, BB * HH);

    for (int L = 0; L < NLAYERS; ++L) {
        const float* Wq_l = Wq + (size_t)L * CC * CC;
        const float* Wk_l = Wk + (size_t)L * CC * CC;
        const float* Wv_l = Wv + (size_t)L * CC * CC;
        const float* Wo_l = Wo + (size_t)L * CC * CC;
        const float* bq_l = bq + (size_t)L * CC;
        const float* bk_l = bk + (size_t)L * CC;
        const float* bv_l = bv + (size_t)L * CC;
        const float* bo_l = bo + (size_t)L * CC;
        const float* erk_l = erk + (size_t)L * (2 * WW + 1) * DKK;
        const float* erv_l = erv + (size_t)L * (2 * WW + 1) * DKK;
        const float* g1_l = g1 + (size_t)L * CC;
        const float* b1_l = b1 + (size_t)L * CC;
        const float* g2_l = g2 + (size_t)L * CC;
        const float* b2_l = b2 + (size_t)L * CC;
        const float* W1_l = W1 + (size_t)L * FF * CC * 3;
        const float* bf1_l = bf1 + (size_t)L * FF;
        const float* W2_l = W2 + (size_t)L * CC * FF * 3;
        const float* bf2_l = bf2 + (size_t)L * CC;

        // QKV projections (bf16 MFMA)
        trans_kernel<false><<<trGrid, 256, 0, stream>>>(xf, mask, Xt);
        mfma_gemm<0><<<gProj, 256, 0, stream>>>(Wq_l, bq_l, Xt, qb, mask, CC, CC, 1);
        mfma_gemm<0><<<gProj, 256, 0, stream>>>(Wk_l, bk_l, Xt, kb, mask, CC, CC, 1);
        mfma_gemm<0><<<gProj, 256, 0, stream>>>(Wv_l, bv_l, Xt, vb, mask, CC, CC, 1);

        // fused attention (single launch)
        fattn_kernel<<<gAttn, 256, 0, stream>>>(qb, kb, vb, mask, erk_l, erv_l, attn);

        // O-projection + residual LN
        trans_kernel<false><<<trGrid, 256, 0, stream>>>(attn, mask, Xt);
        mfma_gemm<0><<<gProj, 256, 0, stream>>>(Wo_l, bo_l, Xt, yb, mask, CC, CC, 1);
        addln_kernel<<<BB * TT, 128, 0, stream>>>(xf, yb, g1_l, b1_l, mask, 0);

        // FFN
        trans_kernel<true><<<trGrid, 256, 0, stream>>>(xf, mask, Xt);
        mfma_gemm<1><<<gConv1, 256, 0, stream>>>(W1_l, bf1_l, Xt, Midt, mask, FF, CC, 3);
        mfma_gemm<0><<<gProj, 256, 0, stream>>>(W2_l, bf2_l, Midt, yb, mask, CC, FF, 3);
        addln_kernel<<<BB * TT, 128, 0, stream>>>(xf, yb, g2_l, b2_l, mask, 1);
    }

    final_kernel<<<eltBlocks, 256, 0, stream>>>(xf, mask, (float*)d_out);
}

// Round 6
// 2550.080 us; speedup vs baseline: 6.0786x; 3.0059x over previous
//
#include <hip/hip_runtime.h>

// ---------------------------------------------------------------------------
// VITS-style relative-attention encoder, MI355X round 6.
// Change vs round 5 (7.66 ms): rocprof showed conv1/conv2 mfma_gemm at 477 us
// each (MfmaUtil 2%, FETCH 282 MB) -- latency-bound on the strided fp32 W
// gather (stride 12 B for ntaps=3). Fix: per-layer weight pre-conversion to
// bf16 [tap][O][K] (wcvt kernel, coalesced), GEMM K-loop now stages W/X with
// 16B uint4 loads, BK=64 per barrier, pad 72 (4-bank row step, 2-way = free).
// Attention/LN/transpose unchanged from round 5.
// ---------------------------------------------------------------------------

#define NLAYERS 6
#define BB 8
#define TT 512
#define CC 512
#define FF 2048
#define HH 8
#define DKK 64
#define WW 10

static_assert(CC == HH * DKK, "");

typedef __attribute__((ext_vector_type(8))) short short8;   // 8 bf16 = 4 VGPRs
typedef __attribute__((ext_vector_type(4))) float f32x4;
typedef unsigned short ushort;

__device__ __forceinline__ ushort f2bs(float f) {   // fp32 -> bf16 RNE
    unsigned u = __float_as_uint(f);
    u = (u + 0x7FFFu + ((u >> 16) & 1u)) >> 16;
    return (ushort)u;
}
__device__ __forceinline__ float bf2f(ushort u) {
    return __uint_as_float(((unsigned)u) << 16);
}

__device__ __forceinline__ float wave_sum(float v) {
    #pragma unroll
    for (int off = 32; off > 0; off >>= 1) v += __shfl_xor(v, off, 64);
    return v;
}

// ---------------------------------------------------------------------------
__global__ __launch_bounds__(256) void init_kernel(const float* __restrict__ x,
                                                   const float* __restrict__ mask,
                                                   float* __restrict__ xf) {
    size_t i = (size_t)blockIdx.x * 256 + threadIdx.x;
    const size_t total = (size_t)BB * CC * TT;
    if (i >= total) return;
    int t = (int)(i % TT);
    int b = (int)(i / ((size_t)CC * TT));
    xf[i] = x[i] * mask[b * TT + t];
}

__global__ __launch_bounds__(256) void final_kernel(const float* __restrict__ xf,
                                                    const float* __restrict__ mask,
                                                    float* __restrict__ out) {
    size_t i = (size_t)blockIdx.x * 256 + threadIdx.x;
    const size_t total = (size_t)BB * CC * TT;
    if (i >= total) return;
    int t = (int)(i % TT);
    int b = (int)(i / ((size_t)CC * TT));
    out[i] = xf[i] * mask[b * TT + t];
}

// ---------------------------------------------------------------------------
// W fp32 [O][K][ntaps] -> Wt bf16 [tap][O][K]  (coalesced writes)
__global__ __launch_bounds__(256) void wcvt_kernel(const float* __restrict__ W,
                                                   ushort* __restrict__ Wt,
                                                   int O, int K, int ntaps) {
    const size_t n = (size_t)ntaps * O * K;
    size_t i = (size_t)blockIdx.x * 256 + threadIdx.x;
    if (i >= n) return;
    const int c = (int)(i % K);
    const int o = (int)((i / K) % O);
    const int tap = (int)(i / ((size_t)K * O));
    Wt[i] = f2bs(W[((size_t)o * K + c) * ntaps + tap]);
}

// ---------------------------------------------------------------------------
// fp32 [B,C,T] -> bf16 [B,T,C], optional mask over t.
template <bool MASK>
__global__ __launch_bounds__(256) void trans_kernel(const float* __restrict__ in,
                                                    const float* __restrict__ mask,
                                                    ushort* __restrict__ out) {
    __shared__ float tile[32][33];
    const int t0 = blockIdx.x * 32;
    const int c0 = blockIdx.y * 32;
    const int b = blockIdx.z;
    const int col = threadIdx.x & 31;
    const int row = threadIdx.x >> 5;  // 0..7
    const float* src = in + ((size_t)b * CC + c0) * TT + t0;
    #pragma unroll
    for (int r = 0; r < 32; r += 8)
        tile[row + r][col] = src[(size_t)(row + r) * TT + col];   // tile[c][t]
    __syncthreads();
    ushort* dst = out + ((size_t)b * TT + t0) * CC + c0;
    #pragma unroll
    for (int r = 0; r < 32; r += 8) {
        const int t = row + r;
        const float m = MASK ? mask[b * TT + t0 + t] : 1.f;
        dst[(size_t)t * CC + col] = f2bs(tile[col][t] * m);
    }
}

// ---------------------------------------------------------------------------
// D[t][o] = sum_{tap,c} Xt[b][t+tap-1][c] * Wt[tap][o][c]   (bf16 MFMA)
// MODE 0: Out fp32 [B,O,T] = D + bias
// MODE 1: Out bf16 [B,T,O] = relu(D + bias) * mask[t]
template <int MODE>
__global__ __launch_bounds__(256) void mfma_gemm(const ushort* __restrict__ Wt,
                                                 const float* __restrict__ bias,
                                                 const ushort* __restrict__ Xt,
                                                 void* __restrict__ Out,
                                                 const float* __restrict__ mask,
                                                 int O, int K, int ntaps) {
    const int t0 = blockIdx.x * 64;
    const int o0 = blockIdx.y * 64;
    const int b = blockIdx.z;
    const int tid = threadIdx.x;
    const int wid = tid >> 6;
    const int lane = tid & 63;
    const int ln = lane & 15;
    const int q = lane >> 4;
    const int wm = wid & 1;   // t-half
    const int wn = wid >> 1;  // o-half

    __shared__ ushort Ws[64][72];  // [o][c], row step 144B = 4 banks -> 2-way
    __shared__ ushort Xs[64][72];  // [t][c]

    f32x4 acc[2][2] = {};

    const ushort* Xb = Xt + (size_t)b * TT * K;
    const int r8 = tid >> 2;          // staging row 0..63
    const int c16 = (tid & 3) << 4;   // staging col 0,16,32,48 (shorts)

    for (int tap = 0; tap < ntaps; ++tap) {
        const int shift = (ntaps > 1) ? (tap - 1) : 0;
        const int gt = t0 + r8 + shift;
        const bool okt = (gt >= 0) && (gt < TT);
        const ushort* Xrow = Xb + (size_t)(okt ? gt : 0) * K;
        const ushort* Wrow = Wt + ((size_t)tap * O + o0 + r8) * K;
        for (int c0 = 0; c0 < K; c0 += 64) {
            *(uint4*)&Ws[r8][c16]     = *(const uint4*)(Wrow + c0 + c16);
            *(uint4*)&Ws[r8][c16 + 8] = *(const uint4*)(Wrow + c0 + c16 + 8);
            uint4 xv0 = make_uint4(0u, 0u, 0u, 0u);
            uint4 xv1 = make_uint4(0u, 0u, 0u, 0u);
            if (okt) {
                xv0 = *(const uint4*)(Xrow + c0 + c16);
                xv1 = *(const uint4*)(Xrow + c0 + c16 + 8);
            }
            *(uint4*)&Xs[r8][c16] = xv0;
            *(uint4*)&Xs[r8][c16 + 8] = xv1;
            __syncthreads();
            #pragma unroll
            for (int kk = 0; kk < 2; ++kk) {
                short8 afr[2], bfr[2];
                #pragma unroll
                for (int mi = 0; mi < 2; ++mi)
                    afr[mi] = *(const short8*)&Xs[wm * 32 + mi * 16 + ln][kk * 32 + q * 8];
                #pragma unroll
                for (int ni = 0; ni < 2; ++ni)
                    bfr[ni] = *(const short8*)&Ws[wn * 32 + ni * 16 + ln][kk * 32 + q * 8];
                #pragma unroll
                for (int mi = 0; mi < 2; ++mi)
                    #pragma unroll
                    for (int ni = 0; ni < 2; ++ni)
                        acc[mi][ni] = __builtin_amdgcn_mfma_f32_16x16x32_bf16(
                            afr[mi], bfr[ni], acc[mi][ni], 0, 0, 0);
            }
            __syncthreads();
        }
    }

    #pragma unroll
    for (int ni = 0; ni < 2; ++ni) {
        const int o = o0 + wn * 32 + ni * 16 + ln;
        const float bv = bias[o];
        #pragma unroll
        for (int mi = 0; mi < 2; ++mi) {
            const int tb = t0 + wm * 32 + mi * 16 + q * 4;
            if (MODE == 0) {
                f32x4 v;
                #pragma unroll
                for (int r = 0; r < 4; ++r) v[r] = acc[mi][ni][r] + bv;
                *(f32x4*)((float*)Out + ((size_t)b * O + o) * TT + tb) = v;
            } else {
                ushort* Op = (ushort*)Out;
                #pragma unroll
                for (int r = 0; r < 4; ++r) {
                    float v = acc[mi][ni][r] + bv;
                    v = fmaxf(v, 0.f) * mask[b * TT + tb + r];
                    Op[((size_t)b * TT + tb + r) * (size_t)O + o] = f2bs(v);
                }
            }
        }
    }
}

// ---------------------------------------------------------------------------
// Fused relative-position attention (flash-style, bf16 MFMA, online softmax).
__global__ __launch_bounds__(256) void fattn_kernel(const float* __restrict__ qg,
                                                    const float* __restrict__ kg,
                                                    const float* __restrict__ vg,
                                                    const float* __restrict__ mask,
                                                    const float* __restrict__ erk,
                                                    const float* __restrict__ erv,
                                                    float* __restrict__ attn) {
    const int t0 = blockIdx.x * 64;
    const int bh = blockIdx.y;
    const int b = bh >> 3, h = bh & 7;
    const int tid = threadIdx.x;
    const int wm = tid >> 6;
    const int lane = tid & 63;
    const int ln = lane & 15;
    const int q4 = lane >> 4;

    __shared__ ushort Qs[64][72];
    __shared__ ushort Ks[64][72];
    __shared__ ushort Vs[64][72];
    __shared__ ushort Ps[64][72];
    __shared__ float rel[64][2 * WW + 1];
    __shared__ float ervs[2 * WW + 1][DKK];
    __shared__ float mtile[64];
    __shared__ float mstile[64];

    const size_t base = ((size_t)b * CC + h * DKK) * TT;

    {
        const int d = tid >> 2;
        const int tg = (tid & 3) << 4;
        const float* Qp = qg + base + (size_t)d * TT + t0 + tg;
        #pragma unroll
        for (int i = 0; i < 16; i += 4) {
            f32x4 v = *(const f32x4*)(Qp + i);
            #pragma unroll
            for (int u = 0; u < 4; ++u)
                Qs[tg + i + u][d] = f2bs(v[u] * 0.125f);
        }
    }
    if (tid < 64) mtile[tid] = mask[b * TT + t0 + tid];
    for (int idx = tid; idx < (2 * WW + 1) * DKK; idx += 256)
        ervs[idx / DKK][idx % DKK] = erv[idx];
    __syncthreads();

    for (int idx = tid; idx < 64 * (2 * WW + 1); idx += 256) {
        const int t = idx / (2 * WW + 1), w = idx % (2 * WW + 1);
        float s = 0.f;
        for (int d = 0; d < DKK; ++d)
            s += bf2f(Qs[t][d]) * erk[w * DKK + d];
        rel[t][w] = s;
    }
    __syncthreads();

    float m_run[4], l_run[4];
    #pragma unroll
    for (int r = 0; r < 4; ++r) { m_run[r] = -1e30f; l_run[r] = 0.f; }
    f32x4 Oacc[4] = {};
    f32x4 Racc[4] = {};

    for (int s0 = 0; s0 < TT; s0 += 64) {
        {
            const int d = tid >> 2;
            const int sg = (tid & 3) << 4;
            const float* Kp = kg + base + (size_t)d * TT + s0 + sg;
            const float* Vp = vg + base + (size_t)d * TT + s0 + sg;
            ushort tmpv[16];
            #pragma unroll
            for (int i = 0; i < 16; i += 4) {
                f32x4 kv = *(const f32x4*)(Kp + i);
                f32x4 vv = *(const f32x4*)(Vp + i);
                #pragma unroll
                for (int u = 0; u < 4; ++u) {
                    Ks[sg + i + u][d] = f2bs(kv[u]);
                    tmpv[i + u] = f2bs(vv[u]);
                }
            }
            *(uint4*)&Vs[d][sg] = *(const uint4*)tmpv;
            *(uint4*)&Vs[d][sg + 8] = *(const uint4*)(tmpv + 8);
        }
        if (tid < 64) mstile[tid] = mask[b * TT + s0 + tid];
        __syncthreads();

        f32x4 accs[4] = {};
        {
            short8 a0 = *(const short8*)&Qs[wm * 16 + ln][q4 * 8];
            short8 a1 = *(const short8*)&Qs[wm * 16 + ln][32 + q4 * 8];
            #pragma unroll
            for (int ni = 0; ni < 4; ++ni) {
                short8 b0 = *(const short8*)&Ks[ni * 16 + ln][q4 * 8];
                short8 b1 = *(const short8*)&Ks[ni * 16 + ln][32 + q4 * 8];
                accs[ni] = __builtin_amdgcn_mfma_f32_16x16x32_bf16(a0, b0, accs[ni], 0, 0, 0);
                accs[ni] = __builtin_amdgcn_mfma_f32_16x16x32_bf16(a1, b1, accs[ni], 0, 0, 0);
            }
        }

        float mx[4];
        #pragma unroll
        for (int r = 0; r < 4; ++r) {
            const int tl = wm * 16 + q4 * 4 + r;
            const float mt = mtile[tl];
            float best = -1e30f;
            #pragma unroll
            for (int ni = 0; ni < 4; ++ni) {
                const int sl = ni * 16 + ln;
                const int wb = (s0 + sl) - (t0 + tl) + WW;
                float v = accs[ni][r];
                if ((unsigned)wb <= 2u * WW) v += rel[tl][wb];
                if (mt * mstile[sl] == 0.f) v = -1e4f;
                accs[ni][r] = v;
                best = fmaxf(best, v);
            }
            #pragma unroll
            for (int off = 8; off >= 1; off >>= 1)
                best = fmaxf(best, __shfl_xor(best, off, 64));
            mx[r] = best;
        }

        #pragma unroll
        for (int r = 0; r < 4; ++r) {
            const float mnew = fmaxf(m_run[r], mx[r]);
            const float alpha = __expf(m_run[r] - mnew);
            m_run[r] = mnew;
            float rsum = 0.f;
            #pragma unroll
            for (int ni = 0; ni < 4; ++ni) {
                const float p = __expf(accs[ni][r] - mnew);
                accs[ni][r] = p;
                rsum += p;
            }
            #pragma unroll
            for (int off = 8; off >= 1; off >>= 1)
                rsum += __shfl_xor(rsum, off, 64);
            l_run[r] = l_run[r] * alpha + rsum;
            #pragma unroll
            for (int ni = 0; ni < 4; ++ni) {
                Oacc[ni][r] *= alpha;
                Racc[ni][r] *= alpha;
            }
        }

        #pragma unroll
        for (int ni = 0; ni < 4; ++ni)
            #pragma unroll
            for (int r = 0; r < 4; ++r)
                Ps[wm * 16 + q4 * 4 + r][ni * 16 + ln] = f2bs(accs[ni][r]);
        __syncthreads();

        {
            short8 a0 = *(const short8*)&Ps[wm * 16 + ln][q4 * 8];
            short8 a1 = *(const short8*)&Ps[wm * 16 + ln][32 + q4 * 8];
            #pragma unroll
            for (int ni = 0; ni < 4; ++ni) {
                short8 b0 = *(const short8*)&Vs[ni * 16 + ln][q4 * 8];
                short8 b1 = *(const short8*)&Vs[ni * 16 + ln][32 + q4 * 8];
                Oacc[ni] = __builtin_amdgcn_mfma_f32_16x16x32_bf16(a0, b0, Oacc[ni], 0, 0, 0);
                Oacc[ni] = __builtin_amdgcn_mfma_f32_16x16x32_bf16(a1, b1, Oacc[ni], 0, 0, 0);
            }
        }

        if (s0 + 63 >= t0 - WW && s0 <= t0 + 63 + WW) {
            #pragma unroll
            for (int r = 0; r < 4; ++r) {
                const int tl = wm * 16 + q4 * 4 + r;
                const int tg = t0 + tl;
                for (int w = 0; w <= 2 * WW; ++w) {
                    const int sl = tg + w - WW - s0;
                    if ((unsigned)sl < 64u) {
                        const float p = bf2f(Ps[tl][sl]);
                        #pragma unroll
                        for (int ni = 0; ni < 4; ++ni)
                            Racc[ni][r] += p * ervs[w][ni * 16 + ln];
                    }
                }
            }
        }
        __syncthreads();
    }

    #pragma unroll
    for (int ni = 0; ni < 4; ++ni) {
        const int d = ni * 16 + ln;
        f32x4 o;
        #pragma unroll
        for (int r = 0; r < 4; ++r)
            o[r] = (Oacc[ni][r] + Racc[ni][r]) / l_run[r];
        *(f32x4*)(attn + base + (size_t)d * TT + t0 + wm * 16 + q4 * 4) = o;
    }
}

// ---------------------------------------------------------------------------
__global__ __launch_bounds__(128) void addln_kernel(float* __restrict__ x,
                                                    const float* __restrict__ y,
                                                    const float* __restrict__ g,
                                                    const float* __restrict__ bt,
                                                    const float* __restrict__ mask,
                                                    int maskY) {
    const int b = blockIdx.x / TT;
    const int t = blockIdx.x % TT;
    const float mv = maskY ? mask[b * TT + t] : 1.f;
    const int tid = threadIdx.x;
    float vals[CC / 128];
    float s = 0.f, s2 = 0.f;
    #pragma unroll
    for (int u = 0; u < CC / 128; ++u) {
        const int c = tid + u * 128;
        const size_t idx = ((size_t)b * CC + c) * TT + t;
        const float v = x[idx] + y[idx] * mv;
        vals[u] = v;
        s += v;
        s2 += v * v;
    }
    __shared__ float ws[2], ws2[2];
    const int wid = tid >> 6, lane = tid & 63;
    s = wave_sum(s);
    s2 = wave_sum(s2);
    if (lane == 0) { ws[wid] = s; ws2[wid] = s2; }
    __syncthreads();
    const float tot = ws[0] + ws[1];
    const float tot2 = ws2[0] + ws2[1];
    const float mean = tot * (1.f / CC);
    const float var = tot2 * (1.f / CC) - mean * mean;
    const float rstd = rsqrtf(var + 1e-5f);
    #pragma unroll
    for (int u = 0; u < CC / 128; ++u) {
        const int c = tid + u * 128;
        const size_t idx = ((size_t)b * CC + c) * TT + t;
        x[idx] = (vals[u] - mean) * rstd * g[c] + bt[c];
    }
}

// ---------------------------------------------------------------------------
extern "C" void kernel_launch(void* const* d_in, const int* in_sizes, int n_in,
                              void* d_out, int out_size, void* d_ws, size_t ws_size,
                              hipStream_t stream) {
    const float* x_in = (const float*)d_in[0];
    const float* mask = (const float*)d_in[1];
    const float* Wq = (const float*)d_in[2];
    const float* bq = (const float*)d_in[3];
    const float* Wk = (const float*)d_in[4];
    const float* bk = (const float*)d_in[5];
    const float* Wv = (const float*)d_in[6];
    const float* bv = (const float*)d_in[7];
    const float* Wo = (const float*)d_in[8];
    const float* bo = (const float*)d_in[9];
    const float* erk = (const float*)d_in[10];
    const float* erv = (const float*)d_in[11];
    const float* g1 = (const float*)d_in[12];
    const float* b1 = (const float*)d_in[13];
    const float* g2 = (const float*)d_in[14];
    const float* b2 = (const float*)d_in[15];
    const float* W1 = (const float*)d_in[16];
    const float* bf1 = (const float*)d_in[17];
    const float* W2 = (const float*)d_in[18];
    const float* bf2 = (const float*)d_in[19];

    // ws layout: xf 8 | Xt 4 | qb 8 | kb 8 | vb 8 | attn 8 | yb 8 |
    //            Wqt/Wkt/Wvt/Wot 4x0.5 | W1t 6.3 | W2t 6.3   (MiB, ~67 total)
    // Midt (bf16 [B,T,F], 16 MiB) aliases qb+kb during the FFN.
    const size_t BCT = (size_t)BB * CC * TT;  // 2,097,152
    float* xf = (float*)d_ws;
    ushort* Xt = (ushort*)(xf + BCT);
    float* qb = (float*)(Xt + BCT);
    float* kb = qb + BCT;
    float* vb = kb + BCT;
    float* attn = vb + BCT;
    float* yb = attn + BCT;
    ushort* Wqt = (ushort*)(yb + BCT);
    ushort* Wkt = Wqt + (size_t)CC * CC;
    ushort* Wvt = Wkt + (size_t)CC * CC;
    ushort* Wot = Wvt + (size_t)CC * CC;
    ushort* W1t = Wot + (size_t)CC * CC;            // [3][FF][CC]
    ushort* W2t = W1t + (size_t)3 * FF * CC;        // [3][CC][FF]
    ushort* Midt = (ushort*)qb;                     // [B,T,F] bf16

    const int eltBlocks = (int)((BCT + 255) / 256);
    init_kernel<<<eltBlocks, 256, 0, stream>>>(x_in, mask, xf);

    const dim3 trGrid(TT / 32, CC / 32, BB);
    const dim3 gProj(TT / 64, CC / 64, BB);
    const dim3 gConv1(TT / 64, FF / 64, BB);
    const dim3 gAttn(TT / 64, BB * HH);
    const int nQ = CC * CC;                   // elems per qkvo weight
    const int nC = 3 * FF * CC;               // elems per conv weight

    for (int L = 0; L < NLAYERS; ++L) {
        const float* Wq_l = Wq + (size_t)L * nQ;
        const float* Wk_l = Wk + (size_t)L * nQ;
        const float* Wv_l = Wv + (size_t)L * nQ;
        const float* Wo_l = Wo + (size_t)L * nQ;
        const float* bq_l = bq + (size_t)L * CC;
        const float* bk_l = bk + (size_t)L * CC;
        const float* bv_l = bv + (size_t)L * CC;
        const float* bo_l = bo + (size_t)L * CC;
        const float* erk_l = erk + (size_t)L * (2 * WW + 1) * DKK;
        const float* erv_l = erv + (size_t)L * (2 * WW + 1) * DKK;
        const float* g1_l = g1 + (size_t)L * CC;
        const float* b1_l = b1 + (size_t)L * CC;
        const float* g2_l = g2 + (size_t)L * CC;
        const float* b2_l = b2 + (size_t)L * CC;
        const float* W1_l = W1 + (size_t)L * nC;
        const float* bf1_l = bf1 + (size_t)L * FF;
        const float* W2_l = W2 + (size_t)L * nC;
        const float* bf2_l = bf2 + (size_t)L * CC;

        // weight pre-conversion (bf16, [tap][O][K])
        wcvt_kernel<<<(nQ + 255) / 256, 256, 0, stream>>>(Wq_l, Wqt, CC, CC, 1);
        wcvt_kernel<<<(nQ + 255) / 256, 256, 0, stream>>>(Wk_l, Wkt, CC, CC, 1);
        wcvt_kernel<<<(nQ + 255) / 256, 256, 0, stream>>>(Wv_l, Wvt, CC, CC, 1);
        wcvt_kernel<<<(nQ + 255) / 256, 256, 0, stream>>>(Wo_l, Wot, CC, CC, 1);
        wcvt_kernel<<<(nC + 255) / 256, 256, 0, stream>>>(W1_l, W1t, FF, CC, 3);
        wcvt_kernel<<<(nC + 255) / 256, 256, 0, stream>>>(W2_l, W2t, CC, FF, 3);

        // QKV projections (bf16 MFMA)
        trans_kernel<false><<<trGrid, 256, 0, stream>>>(xf, mask, Xt);
        mfma_gemm<0><<<gProj, 256, 0, stream>>>(Wqt, bq_l, Xt, qb, mask, CC, CC, 1);
        mfma_gemm<0><<<gProj, 256, 0, stream>>>(Wkt, bk_l, Xt, kb, mask, CC, CC, 1);
        mfma_gemm<0><<<gProj, 256, 0, stream>>>(Wvt, bv_l, Xt, vb, mask, CC, CC, 1);

        // fused attention (single launch)
        fattn_kernel<<<gAttn, 256, 0, stream>>>(qb, kb, vb, mask, erk_l, erv_l, attn);

        // O-projection + residual LN
        trans_kernel<false><<<trGrid, 256, 0, stream>>>(attn, mask, Xt);
        mfma_gemm<0><<<gProj, 256, 0, stream>>>(Wot, bo_l, Xt, yb, mask, CC, CC, 1);
        addln_kernel<<<BB * TT, 128, 0, stream>>>(xf, yb, g1_l, b1_l, mask, 0);

        // FFN
        trans_kernel<true><<<trGrid, 256, 0, stream>>>(xf, mask, Xt);
        mfma_gemm<1><<<gConv1, 256, 0, stream>>>(W1t, bf1_l, Xt, Midt, mask, FF, CC, 3);
        mfma_gemm<0><<<gProj, 256, 0, stream>>>(W2t, bf2_l, Midt, yb, mask, CC, FF, 3);
        addln_kernel<<<BB * TT, 128, 0, stream>>>(xf, yb, g2_l, b2_l, mask, 1);
    }

    final_kernel<<<eltBlocks, 256, 0, stream>>>(xf, mask, (float*)d_out);
}

// Round 7
// 2195.386 us; speedup vs baseline: 7.0607x; 1.1616x over previous
//
#include <hip/hip_runtime.h>

// ---------------------------------------------------------------------------
// VITS-style relative-attention encoder, MI355X round 7.
// vs round 6 (2.55 ms): (1) GEMMs rebuilt m93-style: 128-wide tiles, BK=32,
// register-prefetch dbuf (16 MFMAs/wave per barrier, loads overlap MFMA);
// (2) QKV fused to one GEMM (N=1536) emitting q,k bf16 [B,T,C] + v bf16
// [B,C,T] so fattn stages with pure uint4 copies (no transpose/convert);
// (3) addln emits bf16 transposed activations (no trans launches), fattn
// emits bf16 [B,T,C] for O-proj, one wcvt per layer. ~52 launches total.
// ---------------------------------------------------------------------------

#define NLAYERS 6
#define BB 8
#define TT 512
#define CC 512
#define FF 2048
#define HH 8
#define DKK 64
#define WW 10

static_assert(CC == HH * DKK, "");

typedef __attribute__((ext_vector_type(8))) short short8;   // 8 bf16
typedef __attribute__((ext_vector_type(4))) float f32x4;
typedef unsigned short ushort;

#define BCTS ((size_t)BB * CC * TT)   // elements per [B,C,T] tensor

__device__ __forceinline__ ushort f2bs(float f) {   // fp32 -> bf16 RNE
    unsigned u = __float_as_uint(f);
    u = (u + 0x7FFFu + ((u >> 16) & 1u)) >> 16;
    return (ushort)u;
}
__device__ __forceinline__ float bf2f(ushort u) {
    return __uint_as_float(((unsigned)u) << 16);
}
__device__ __forceinline__ float wave_sum(float v) {
    #pragma unroll
    for (int off = 32; off > 0; off >>= 1) v += __shfl_xor(v, off, 64);
    return v;
}

// ---------------------------------------------------------------------------
__global__ __launch_bounds__(256) void init_kernel(const float* __restrict__ x,
                                                   const float* __restrict__ mask,
                                                   float* __restrict__ xf) {
    size_t i = (size_t)blockIdx.x * 256 + threadIdx.x;
    if (i >= BCTS) return;
    int t = (int)(i % TT);
    int b = (int)(i / ((size_t)CC * TT));
    xf[i] = x[i] * mask[b * TT + t];
}

__global__ __launch_bounds__(256) void final_kernel(const float* __restrict__ xf,
                                                    const float* __restrict__ mask,
                                                    float* __restrict__ out) {
    size_t i = (size_t)blockIdx.x * 256 + threadIdx.x;
    if (i >= BCTS) return;
    int t = (int)(i % TT);
    int b = (int)(i / ((size_t)CC * TT));
    out[i] = xf[i] * mask[b * TT + t];
}

// fp32 [B,C,T] -> bf16 [B,T,C]  (used once at start)
__global__ __launch_bounds__(256) void trans_kernel(const float* __restrict__ in,
                                                    ushort* __restrict__ out) {
    __shared__ float tile[32][33];
    const int t0 = blockIdx.x * 32;
    const int c0 = blockIdx.y * 32;
    const int b = blockIdx.z;
    const int col = threadIdx.x & 31;
    const int row = threadIdx.x >> 5;
    const float* src = in + ((size_t)b * CC + c0) * TT + t0;
    #pragma unroll
    for (int r = 0; r < 32; r += 8)
        tile[row + r][col] = src[(size_t)(row + r) * TT + col];
    __syncthreads();
    ushort* dst = out + ((size_t)b * TT + t0) * CC + c0;
    #pragma unroll
    for (int r = 0; r < 32; r += 8)
        dst[(size_t)(row + r) * CC + col] = f2bs(tile[col][row + r]);
}

// ---------------------------------------------------------------------------
// Per-layer weight conversion, ONE launch:
//  Wq/Wk/Wv [512][512] -> Wqkv bf16 [1536][512], bqkv fp32 [1536]
//  Wo -> Wot bf16 [512][512]
//  W1 [2048][512][3] -> W1t bf16 [3][2048][512]
//  W2 [512][2048][3] -> W2t bf16 [3][512][2048]
__global__ __launch_bounds__(256) void wcvt_layer(const float* __restrict__ Wq,
                                                  const float* __restrict__ Wk,
                                                  const float* __restrict__ Wv,
                                                  const float* __restrict__ bq,
                                                  const float* __restrict__ bk,
                                                  const float* __restrict__ bv,
                                                  const float* __restrict__ Wo,
                                                  const float* __restrict__ W1,
                                                  const float* __restrict__ W2,
                                                  ushort* __restrict__ Wqkv,
                                                  float* __restrict__ bqkv,
                                                  ushort* __restrict__ Wot,
                                                  ushort* __restrict__ W1t,
                                                  ushort* __restrict__ W2t) {
    size_t i = (size_t)blockIdx.x * 256 + threadIdx.x;
    if (i < 1536)
        bqkv[i] = (i < 512) ? bq[i] : (i < 1024) ? bk[i - 512] : bv[i - 1024];
    if (i < 786432) {
        const int o = (int)(i >> 9), c = (int)(i & 511);
        const float* src = (o < 512) ? Wq : (o < 1024) ? Wk : Wv;
        Wqkv[i] = f2bs(src[(size_t)(o & 511) * 512 + c]);
        return;
    }
    i -= 786432;
    if (i < 262144) { Wot[i] = f2bs(Wo[i]); return; }
    i -= 262144;
    if (i < 3145728) {
        const int c = (int)(i & 511);
        const int o = (int)((i >> 9) & 2047);
        const int tap = (int)(i >> 20);
        W1t[i] = f2bs(W1[((size_t)o * 512 + c) * 3 + tap]);
        return;
    }
    i -= 3145728;
    if (i < 3145728) {
        const int c = (int)(i & 2047);
        const int o = (int)((i >> 11) & 511);
        const int tap = (int)(i >> 20);
        W2t[i] = f2bs(W2[((size_t)o * 2048 + c) * 3 + tap]);
    }
}

// ---------------------------------------------------------------------------
// 128(M=b*T flattened) x TN tile GEMM, BK=32, register-prefetch dbuf.
//  D[t][o] = sum_{tap,c} Xin[b][t+tap-(taps>1)][c] * Wt[tap][o][c]
// MODE 0: Out fp32 [B,O,T] = D + bias
// MODE 1: Out bf16 [B,T,O] = relu(D + bias) * mask[t]
// MODE 2: QKV (O=1536): q,k -> bf16 [B,T,512]; v -> bf16 [B,512,T]
template <int MODE, int TN>
__global__ __launch_bounds__(256) void gemm128(const ushort* __restrict__ Wt,
                                               const float* __restrict__ bias,
                                               const ushort* __restrict__ Xin,
                                               void* __restrict__ Out,
                                               const float* __restrict__ mask,
                                               int O, int K, int taps, int kcs) {
    const int blk = blockIdx.x;
    const int b = blk >> 2;
    const int t0 = (blk & 3) * 128;
    const int o0 = blockIdx.y * TN;
    const int tid = threadIdx.x;
    const int wid = tid >> 6, lane = tid & 63, ln = lane & 15, q = lane >> 4;
    constexpr int MF = (TN == 128) ? 4 : 2;
    const int msub = (TN == 128) ? (wid & 1) * 64 : wid * 32;
    const int nsub = (TN == 128) ? (wid >> 1) * 64 : 0;

    __shared__ ushort Xs[128][40];
    __shared__ ushort Ws[TN][40];

    f32x4 acc[MF][4] = {};

    const int KC = K >> 5;
    const int NI = taps * KC;
    const int kcm = KC - 1;

    const int rx = tid >> 1;
    const int cx = (tid & 1) << 4;
    const int rw = (TN == 128) ? (tid >> 1) : (tid >> 2);
    const int cw = (TN == 128) ? ((tid & 1) << 4) : ((tid & 3) << 3);

    uint4 xr0, xr1, wr0, wr1;
    const uint4 zero = make_uint4(0u, 0u, 0u, 0u);

    auto load = [&](int it) {
        const int tap = it >> kcs;
        const int c0 = (it & kcm) << 5;
        const int shift = (taps > 1) ? (tap - 1) : 0;
        const int tt = t0 + rx + shift;
        const bool okt = (tt >= 0) && (tt < TT);
        const ushort* xp = Xin + ((size_t)(b * TT + (okt ? tt : 0)) * K + c0 + cx);
        xr0 = okt ? *(const uint4*)xp : zero;
        xr1 = okt ? *(const uint4*)(xp + 8) : zero;
        const ushort* wp = Wt + ((size_t)(tap * O + o0 + rw) * K + c0 + cw);
        wr0 = *(const uint4*)wp;
        if (TN == 128) wr1 = *(const uint4*)(wp + 8);
    };

    load(0);
    for (int it = 0; it < NI; ++it) {
        __syncthreads();
        *(uint4*)&Xs[rx][cx] = xr0;
        *(uint4*)&Xs[rx][cx + 8] = xr1;
        *(uint4*)&Ws[rw][cw] = wr0;
        if (TN == 128) *(uint4*)&Ws[rw][cw + 8] = wr1;
        if (it + 1 < NI) load(it + 1);
        __syncthreads();
        short8 afr[MF], bfr[4];
        #pragma unroll
        for (int mi = 0; mi < MF; ++mi)
            afr[mi] = *(const short8*)&Xs[msub + mi * 16 + ln][q * 8];
        #pragma unroll
        for (int ni = 0; ni < 4; ++ni)
            bfr[ni] = *(const short8*)&Ws[nsub + ni * 16 + ln][q * 8];
        #pragma unroll
        for (int mi = 0; mi < MF; ++mi)
            #pragma unroll
            for (int ni = 0; ni < 4; ++ni)
                acc[mi][ni] = __builtin_amdgcn_mfma_f32_16x16x32_bf16(
                    afr[mi], bfr[ni], acc[mi][ni], 0, 0, 0);
    }

    #pragma unroll
    for (int ni = 0; ni < 4; ++ni) {
        const int o = o0 + nsub + ni * 16 + ln;
        const float bv = bias[o];
        #pragma unroll
        for (int mi = 0; mi < MF; ++mi) {
            const int t = t0 + msub + mi * 16 + q * 4;
            if (MODE == 0) {
                f32x4 v;
                #pragma unroll
                for (int r = 0; r < 4; ++r) v[r] = acc[mi][ni][r] + bv;
                *(f32x4*)((float*)Out + ((size_t)b * O + o) * TT + t) = v;
            } else if (MODE == 1) {
                ushort* Op = (ushort*)Out;
                #pragma unroll
                for (int r = 0; r < 4; ++r) {
                    float v = fmaxf(acc[mi][ni][r] + bv, 0.f) * mask[b * TT + t + r];
                    Op[((size_t)(b * TT) + t + r) * (size_t)O + o] = f2bs(v);
                }
            } else {
                ushort* Op = (ushort*)Out;
                const int which = o >> 9, oo = o & 511;
                if (which < 2) {
                    #pragma unroll
                    for (int r = 0; r < 4; ++r)
                        Op[(size_t)which * BCTS + ((size_t)(b * TT) + t + r) * CC + oo] =
                            f2bs(acc[mi][ni][r] + bv);
                } else {
                    ushort tmp[4];
                    #pragma unroll
                    for (int r = 0; r < 4; ++r) tmp[r] = f2bs(acc[mi][ni][r] + bv);
                    *(uint2*)&Op[2 * BCTS + ((size_t)(b * CC) + oo) * TT + t] =
                        *(const uint2*)tmp;
                }
            }
        }
    }
}

// ---------------------------------------------------------------------------
// Fused relative-position attention. qkvt: q,k bf16 [B,T,C]; v bf16 [B,C,T].
// Output: bf16 [B,T,C] (O-proj input). Scale 1/8 folded into logits.
__global__ __launch_bounds__(256) void fattn_kernel(const ushort* __restrict__ qkvt,
                                                    const float* __restrict__ mask,
                                                    const float* __restrict__ erk,
                                                    const float* __restrict__ erv,
                                                    ushort* __restrict__ xto) {
    const int t0 = blockIdx.x * 64;
    const int bh = blockIdx.y;
    const int b = bh >> 3, h = bh & 7;
    const int tid = threadIdx.x;
    const int wm = tid >> 6;
    const int lane = tid & 63;
    const int ln = lane & 15;
    const int q4 = lane >> 4;

    __shared__ ushort Qs[64][72];
    __shared__ ushort Ks[64][72];
    __shared__ ushort Vs[64][72];
    __shared__ ushort Ps[64][72];
    __shared__ float rel[64][2 * WW + 1];
    __shared__ float ervs[2 * WW + 1][DKK];
    __shared__ float mtile[64];
    __shared__ float mstile[64];

    const int sr = tid >> 2;
    const int sc = (tid & 3) << 4;

    {   // Q rows (t-major, contiguous d)
        const ushort* qp = qkvt + ((size_t)(b * TT + t0 + sr) * CC + h * DKK + sc);
        *(uint4*)&Qs[sr][sc] = *(const uint4*)qp;
        *(uint4*)&Qs[sr][sc + 8] = *(const uint4*)(qp + 8);
    }
    if (tid < 64) mtile[tid] = mask[b * TT + t0 + tid];
    for (int idx = tid; idx < (2 * WW + 1) * DKK; idx += 256)
        ervs[idx / DKK][idx % DKK] = erv[idx];
    __syncthreads();

    for (int idx = tid; idx < 64 * (2 * WW + 1); idx += 256) {
        const int t = idx / (2 * WW + 1), w = idx % (2 * WW + 1);
        float s = 0.f;
        for (int d = 0; d < DKK; ++d)
            s += bf2f(Qs[t][d]) * erk[w * DKK + d];
        rel[t][w] = 0.125f * s;
    }
    __syncthreads();

    float m_run[4], l_run[4];
    #pragma unroll
    for (int r = 0; r < 4; ++r) { m_run[r] = -1e30f; l_run[r] = 0.f; }
    f32x4 Oacc[4] = {};
    f32x4 Racc[4] = {};

    for (int s0 = 0; s0 < TT; s0 += 64) {
        {   // K rows (t-major) + V rows (d-major: already s-contiguous)
            const ushort* kp = qkvt + BCTS + ((size_t)(b * TT + s0 + sr) * CC + h * DKK + sc);
            *(uint4*)&Ks[sr][sc] = *(const uint4*)kp;
            *(uint4*)&Ks[sr][sc + 8] = *(const uint4*)(kp + 8);
            const ushort* vp = qkvt + 2 * BCTS + ((size_t)(b * CC + h * DKK + sr) * TT + s0 + sc);
            *(uint4*)&Vs[sr][sc] = *(const uint4*)vp;
            *(uint4*)&Vs[sr][sc + 8] = *(const uint4*)(vp + 8);
        }
        if (tid < 64) mstile[tid] = mask[b * TT + s0 + tid];
        __syncthreads();

        f32x4 accs[4] = {};
        {
            short8 a0 = *(const short8*)&Qs[wm * 16 + ln][q4 * 8];
            short8 a1 = *(const short8*)&Qs[wm * 16 + ln][32 + q4 * 8];
            #pragma unroll
            for (int ni = 0; ni < 4; ++ni) {
                short8 b0 = *(const short8*)&Ks[ni * 16 + ln][q4 * 8];
                short8 b1 = *(const short8*)&Ks[ni * 16 + ln][32 + q4 * 8];
                accs[ni] = __builtin_amdgcn_mfma_f32_16x16x32_bf16(a0, b0, accs[ni], 0, 0, 0);
                accs[ni] = __builtin_amdgcn_mfma_f32_16x16x32_bf16(a1, b1, accs[ni], 0, 0, 0);
            }
        }

        float mx[4];
        #pragma unroll
        for (int r = 0; r < 4; ++r) {
            const int tl = wm * 16 + q4 * 4 + r;
            const float mt = mtile[tl];
            float best = -1e30f;
            #pragma unroll
            for (int ni = 0; ni < 4; ++ni) {
                const int sl = ni * 16 + ln;
                const int wb = (s0 + sl) - (t0 + tl) + WW;
                float v = accs[ni][r] * 0.125f;
                if ((unsigned)wb <= 2u * WW) v += rel[tl][wb];
                if (mt * mstile[sl] == 0.f) v = -1e4f;
                accs[ni][r] = v;
                best = fmaxf(best, v);
            }
            #pragma unroll
            for (int off = 8; off >= 1; off >>= 1)
                best = fmaxf(best, __shfl_xor(best, off, 64));
            mx[r] = best;
        }

        #pragma unroll
        for (int r = 0; r < 4; ++r) {
            const float mnew = fmaxf(m_run[r], mx[r]);
            const float alpha = __expf(m_run[r] - mnew);
            m_run[r] = mnew;
            float rsum = 0.f;
            #pragma unroll
            for (int ni = 0; ni < 4; ++ni) {
                const float p = __expf(accs[ni][r] - mnew);
                accs[ni][r] = p;
                rsum += p;
            }
            #pragma unroll
            for (int off = 8; off >= 1; off >>= 1)
                rsum += __shfl_xor(rsum, off, 64);
            l_run[r] = l_run[r] * alpha + rsum;
            #pragma unroll
            for (int ni = 0; ni < 4; ++ni) {
                Oacc[ni][r] *= alpha;
                Racc[ni][r] *= alpha;
            }
        }

        #pragma unroll
        for (int ni = 0; ni < 4; ++ni)
            #pragma unroll
            for (int r = 0; r < 4; ++r)
                Ps[wm * 16 + q4 * 4 + r][ni * 16 + ln] = f2bs(accs[ni][r]);
        __syncthreads();

        {
            short8 a0 = *(const short8*)&Ps[wm * 16 + ln][q4 * 8];
            short8 a1 = *(const short8*)&Ps[wm * 16 + ln][32 + q4 * 8];
            #pragma unroll
            for (int ni = 0; ni < 4; ++ni) {
                short8 b0 = *(const short8*)&Vs[ni * 16 + ln][q4 * 8];
                short8 b1 = *(const short8*)&Vs[ni * 16 + ln][32 + q4 * 8];
                Oacc[ni] = __builtin_amdgcn_mfma_f32_16x16x32_bf16(a0, b0, Oacc[ni], 0, 0, 0);
                Oacc[ni] = __builtin_amdgcn_mfma_f32_16x16x32_bf16(a1, b1, Oacc[ni], 0, 0, 0);
            }
        }

        if (s0 + 63 >= t0 - WW && s0 <= t0 + 63 + WW) {
            #pragma unroll
            for (int r = 0; r < 4; ++r) {
                const int tl = wm * 16 + q4 * 4 + r;
                const int tg = t0 + tl;
                for (int w = 0; w <= 2 * WW; ++w) {
                    const int sl = tg + w - WW - s0;
                    if ((unsigned)sl < 64u) {
                        const float p = bf2f(Ps[tl][sl]);
                        #pragma unroll
                        for (int ni = 0; ni < 4; ++ni)
                            Racc[ni][r] += p * ervs[w][ni * 16 + ln];
                    }
                }
            }
        }
        __syncthreads();
    }

    #pragma unroll
    for (int ni = 0; ni < 4; ++ni) {
        const int d = ni * 16 + ln;
        #pragma unroll
        for (int r = 0; r < 4; ++r) {
            const int t = t0 + wm * 16 + q4 * 4 + r;
            xto[((size_t)(b * TT) + t) * CC + h * DKK + d] =
                f2bs((Oacc[ni][r] + Racc[ni][r]) / l_run[r]);
        }
    }
}

// ---------------------------------------------------------------------------
// x = LN(x + y*(maskY?m:1)); also emits Xt bf16 [B,T,C] = x*(maskOut?m:1).
__global__ __launch_bounds__(128) void addln_kernel(float* __restrict__ x,
                                                    const float* __restrict__ y,
                                                    const float* __restrict__ g,
                                                    const float* __restrict__ bt,
                                                    const float* __restrict__ mask,
                                                    int maskY,
                                                    ushort* __restrict__ xtout,
                                                    int maskOut) {
    const int b = blockIdx.x / TT;
    const int t = blockIdx.x % TT;
    const float m = mask[b * TT + t];
    const float mv = maskY ? m : 1.f;
    const float mo = maskOut ? m : 1.f;
    const int tid = threadIdx.x;
    float vals[CC / 128];
    float s = 0.f, s2 = 0.f;
    #pragma unroll
    for (int u = 0; u < CC / 128; ++u) {
        const int c = tid + u * 128;
        const size_t idx = ((size_t)b * CC + c) * TT + t;
        const float v = x[idx] + y[idx] * mv;
        vals[u] = v;
        s += v;
        s2 += v * v;
    }
    __shared__ float ws[2], ws2[2];
    const int wid = tid >> 6, lane = tid & 63;
    s = wave_sum(s);
    s2 = wave_sum(s2);
    if (lane == 0) { ws[wid] = s; ws2[wid] = s2; }
    __syncthreads();
    const float tot = ws[0] + ws[1];
    const float tot2 = ws2[0] + ws2[1];
    const float mean = tot * (1.f / CC);
    const float var = tot2 * (1.f / CC) - mean * mean;
    const float rstd = rsqrtf(var + 1e-5f);
    #pragma unroll
    for (int u = 0; u < CC / 128; ++u) {
        const int c = tid + u * 128;
        const size_t idx = ((size_t)b * CC + c) * TT + t;
        const float outv = (vals[u] - mean) * rstd * g[c] + bt[c];
        x[idx] = outv;
        xtout[((size_t)(b * TT) + t) * CC + c] = f2bs(outv * mo);
    }
}

// ---------------------------------------------------------------------------
extern "C" void kernel_launch(void* const* d_in, const int* in_sizes, int n_in,
                              void* d_out, int out_size, void* d_ws, size_t ws_size,
                              hipStream_t stream) {
    const float* x_in = (const float*)d_in[0];
    const float* mask = (const float*)d_in[1];
    const float* Wq = (const float*)d_in[2];
    const float* bq = (const float*)d_in[3];
    const float* Wk = (const float*)d_in[4];
    const float* bk = (const float*)d_in[5];
    const float* Wv = (const float*)d_in[6];
    const float* bv = (const float*)d_in[7];
    const float* Wo = (const float*)d_in[8];
    const float* bo = (const float*)d_in[9];
    const float* erk = (const float*)d_in[10];
    const float* erv = (const float*)d_in[11];
    const float* g1 = (const float*)d_in[12];
    const float* b1 = (const float*)d_in[13];
    const float* g2 = (const float*)d_in[14];
    const float* b2 = (const float*)d_in[15];
    const float* W1 = (const float*)d_in[16];
    const float* bf1 = (const float*)d_in[17];
    const float* W2 = (const float*)d_in[18];
    const float* bf2 = (const float*)d_in[19];

    // ws: xf 8 | Xt 4 | qkvt 12 | Xto 4 | yb 8 | Midt 16 | weights ~14  (MiB)
    float* xf = (float*)d_ws;
    ushort* Xt = (ushort*)(xf + BCTS);
    ushort* qkvt = Xt + BCTS;
    ushort* Xto = qkvt + 3 * BCTS;
    float* yb = (float*)(Xto + BCTS);
    ushort* Midt = (ushort*)(yb + BCTS);
    ushort* Wqkv = Midt + 4 * BCTS;
    float* bqkv = (float*)(Wqkv + (size_t)1536 * 512);
    ushort* Wot = (ushort*)(bqkv + 1536);
    ushort* W1t = Wot + (size_t)CC * CC;
    ushort* W2t = W1t + (size_t)3 * FF * CC;

    const int eltBlocks = (int)((BCTS + 255) / 256);
    init_kernel<<<eltBlocks, 256, 0, stream>>>(x_in, mask, xf);
    trans_kernel<<<dim3(TT / 32, CC / 32, BB), 256, 0, stream>>>(xf, Xt);

    const size_t nW = 786432 + 262144 + 3145728 + 3145728;  // 7,340,032
    const int wcvtBlocks = (int)((nW + 255) / 256);

    for (int L = 0; L < NLAYERS; ++L) {
        wcvt_layer<<<wcvtBlocks, 256, 0, stream>>>(
            Wq + (size_t)L * CC * CC, Wk + (size_t)L * CC * CC, Wv + (size_t)L * CC * CC,
            bq + (size_t)L * CC, bk + (size_t)L * CC, bv + (size_t)L * CC,
            Wo + (size_t)L * CC * CC,
            W1 + (size_t)L * 3 * FF * CC, W2 + (size_t)L * 3 * FF * CC,
            Wqkv, bqkv, Wot, W1t, W2t);

        // fused QKV (N=1536)
        gemm128<2, 128><<<dim3(32, 12), 256, 0, stream>>>(
            Wqkv, bqkv, Xt, qkvt, mask, 1536, CC, 1, 4);

        // fused attention
        fattn_kernel<<<dim3(TT / 64, BB * HH), 256, 0, stream>>>(
            qkvt, mask, erk + (size_t)L * (2 * WW + 1) * DKK,
            erv + (size_t)L * (2 * WW + 1) * DKK, Xto);

        // O-projection + residual LN (emits masked Xt for conv1)
        gemm128<0, 64><<<dim3(32, 8), 256, 0, stream>>>(
            Wot, bo + (size_t)L * CC, Xto, yb, mask, CC, CC, 1, 4);
        addln_kernel<<<BB * TT, 128, 0, stream>>>(
            xf, yb, g1 + (size_t)L * CC, b1 + (size_t)L * CC, mask, 0, Xt, 1);

        // FFN
        gemm128<1, 128><<<dim3(32, 16), 256, 0, stream>>>(
            W1t, bf1 + (size_t)L * FF, Xt, Midt, mask, FF, CC, 3, 4);
        gemm128<0, 64><<<dim3(32, 8), 256, 0, stream>>>(
            W2t, bf2 + (size_t)L * CC, Midt, yb, mask, CC, FF, 3, 6);
        addln_kernel<<<BB * TT, 128, 0, stream>>>(
            xf, yb, g2 + (size_t)L * CC, b2 + (size_t)L * CC, mask, 1, Xt, 0);
    }

    final_kernel<<<eltBlocks, 256, 0, stream>>>(xf, mask, (float*)d_out);
}

// Round 8
// 2025.640 us; speedup vs baseline: 7.6523x; 1.0838x over previous
//
#include <hip/hip_runtime.h>

// ---------------------------------------------------------------------------
// VITS-style relative-attention encoder, MI355X round 8.
// vs round 7 (2.20 ms): conv GEMMs were latency-bound at 1 block/CU
// (Occupancy 10.6%, MfmaUtil 10%). New conv_gemm kernel: stages a 130-row
// halo X tile once per 32-col c-chunk and computes ALL 3 taps from LDS
// (3x MFMA intensity per barrier, 3x fewer X reads); conv2 additionally
// K-splits (grid.z=2) into fp32 partials whose reduction (+bias+mask) is
// fused into addln. conv2: 512 blocks (2/CU), NI 192->32. conv1: 512 blocks,
// NI 48->16. QKV/O-proj/fattn/addln structure unchanged from round 7.
// ---------------------------------------------------------------------------

#define NLAYERS 6
#define BB 8
#define TT 512
#define CC 512
#define FF 2048
#define HH 8
#define DKK 64
#define WW 10

static_assert(CC == HH * DKK, "");

typedef __attribute__((ext_vector_type(8))) short short8;   // 8 bf16
typedef __attribute__((ext_vector_type(4))) float f32x4;
typedef unsigned short ushort;

#define BCTS ((size_t)BB * CC * TT)   // elements per [B,C,T] tensor

__device__ __forceinline__ ushort f2bs(float f) {   // fp32 -> bf16 RNE
    unsigned u = __float_as_uint(f);
    u = (u + 0x7FFFu + ((u >> 16) & 1u)) >> 16;
    return (ushort)u;
}
__device__ __forceinline__ float bf2f(ushort u) {
    return __uint_as_float(((unsigned)u) << 16);
}
__device__ __forceinline__ float wave_sum(float v) {
    #pragma unroll
    for (int off = 32; off > 0; off >>= 1) v += __shfl_xor(v, off, 64);
    return v;
}

// ---------------------------------------------------------------------------
__global__ __launch_bounds__(256) void init_kernel(const float* __restrict__ x,
                                                   const float* __restrict__ mask,
                                                   float* __restrict__ xf) {
    size_t i = (size_t)blockIdx.x * 256 + threadIdx.x;
    if (i >= BCTS) return;
    int t = (int)(i % TT);
    int b = (int)(i / ((size_t)CC * TT));
    xf[i] = x[i] * mask[b * TT + t];
}

__global__ __launch_bounds__(256) void final_kernel(const float* __restrict__ xf,
                                                    const float* __restrict__ mask,
                                                    float* __restrict__ out) {
    size_t i = (size_t)blockIdx.x * 256 + threadIdx.x;
    if (i >= BCTS) return;
    int t = (int)(i % TT);
    int b = (int)(i / ((size_t)CC * TT));
    out[i] = xf[i] * mask[b * TT + t];
}

// fp32 [B,C,T] -> bf16 [B,T,C]  (once at start)
__global__ __launch_bounds__(256) void trans_kernel(const float* __restrict__ in,
                                                    ushort* __restrict__ out) {
    __shared__ float tile[32][33];
    const int t0 = blockIdx.x * 32;
    const int c0 = blockIdx.y * 32;
    const int b = blockIdx.z;
    const int col = threadIdx.x & 31;
    const int row = threadIdx.x >> 5;
    const float* src = in + ((size_t)b * CC + c0) * TT + t0;
    #pragma unroll
    for (int r = 0; r < 32; r += 8)
        tile[row + r][col] = src[(size_t)(row + r) * TT + col];
    __syncthreads();
    ushort* dst = out + ((size_t)b * TT + t0) * CC + c0;
    #pragma unroll
    for (int r = 0; r < 32; r += 8)
        dst[(size_t)(row + r) * CC + col] = f2bs(tile[col][row + r]);
}

// ---------------------------------------------------------------------------
// Per-layer weight conversion, ONE launch (layouts as round 7).
__global__ __launch_bounds__(256) void wcvt_layer(const float* __restrict__ Wq,
                                                  const float* __restrict__ Wk,
                                                  const float* __restrict__ Wv,
                                                  const float* __restrict__ bq,
                                                  const float* __restrict__ bk,
                                                  const float* __restrict__ bv,
                                                  const float* __restrict__ Wo,
                                                  const float* __restrict__ W1,
                                                  const float* __restrict__ W2,
                                                  ushort* __restrict__ Wqkv,
                                                  float* __restrict__ bqkv,
                                                  ushort* __restrict__ Wot,
                                                  ushort* __restrict__ W1t,
                                                  ushort* __restrict__ W2t) {
    size_t i = (size_t)blockIdx.x * 256 + threadIdx.x;
    if (i < 1536)
        bqkv[i] = (i < 512) ? bq[i] : (i < 1024) ? bk[i - 512] : bv[i - 1024];
    if (i < 786432) {
        const int o = (int)(i >> 9), c = (int)(i & 511);
        const float* src = (o < 512) ? Wq : (o < 1024) ? Wk : Wv;
        Wqkv[i] = f2bs(src[(size_t)(o & 511) * 512 + c]);
        return;
    }
    i -= 786432;
    if (i < 262144) { Wot[i] = f2bs(Wo[i]); return; }
    i -= 262144;
    if (i < 3145728) {
        const int c = (int)(i & 511);
        const int o = (int)((i >> 9) & 2047);
        const int tap = (int)(i >> 20);
        W1t[i] = f2bs(W1[((size_t)o * 512 + c) * 3 + tap]);
        return;
    }
    i -= 3145728;
    if (i < 3145728) {
        const int c = (int)(i & 2047);
        const int o = (int)((i >> 11) & 511);
        const int tap = (int)(i >> 20);
        W2t[i] = f2bs(W2[((size_t)o * 2048 + c) * 3 + tap]);
    }
}

// ---------------------------------------------------------------------------
// Generic 128xTN GEMM (taps folded sequentially) -- used for QKV and O-proj.
// MODE 0: Out fp32 [B,O,T] = D + bias
// MODE 2: QKV (O=1536): q,k -> bf16 [B,T,512]; v -> bf16 [B,512,T]
template <int MODE, int TN>
__global__ __launch_bounds__(256) void gemm128(const ushort* __restrict__ Wt,
                                               const float* __restrict__ bias,
                                               const ushort* __restrict__ Xin,
                                               void* __restrict__ Out,
                                               const float* __restrict__ mask,
                                               int O, int K, int taps, int kcs) {
    const int blk = blockIdx.x;
    const int b = blk >> 2;
    const int t0 = (blk & 3) * 128;
    const int o0 = blockIdx.y * TN;
    const int tid = threadIdx.x;
    const int wid = tid >> 6, lane = tid & 63, ln = lane & 15, q = lane >> 4;
    constexpr int MF = (TN == 128) ? 4 : 2;
    const int msub = (TN == 128) ? (wid & 1) * 64 : wid * 32;
    const int nsub = (TN == 128) ? (wid >> 1) * 64 : 0;

    __shared__ ushort Xs[128][40];
    __shared__ ushort Ws[TN][40];

    f32x4 acc[MF][4] = {};

    const int KC = K >> 5;
    const int NI = taps * KC;
    const int kcm = KC - 1;

    const int rx = tid >> 1;
    const int cx = (tid & 1) << 4;
    const int rw = (TN == 128) ? (tid >> 1) : (tid >> 2);
    const int cw = (TN == 128) ? ((tid & 1) << 4) : ((tid & 3) << 3);

    uint4 xr0, xr1, wr0, wr1;
    const uint4 zero = make_uint4(0u, 0u, 0u, 0u);

    auto load = [&](int it) {
        const int tap = it >> kcs;
        const int c0 = (it & kcm) << 5;
        const int shift = (taps > 1) ? (tap - 1) : 0;
        const int tt = t0 + rx + shift;
        const bool okt = (tt >= 0) && (tt < TT);
        const ushort* xp = Xin + ((size_t)(b * TT + (okt ? tt : 0)) * K + c0 + cx);
        xr0 = okt ? *(const uint4*)xp : zero;
        xr1 = okt ? *(const uint4*)(xp + 8) : zero;
        const ushort* wp = Wt + ((size_t)(tap * O + o0 + rw) * K + c0 + cw);
        wr0 = *(const uint4*)wp;
        if (TN == 128) wr1 = *(const uint4*)(wp + 8);
    };

    load(0);
    for (int it = 0; it < NI; ++it) {
        __syncthreads();
        *(uint4*)&Xs[rx][cx] = xr0;
        *(uint4*)&Xs[rx][cx + 8] = xr1;
        *(uint4*)&Ws[rw][cw] = wr0;
        if (TN == 128) *(uint4*)&Ws[rw][cw + 8] = wr1;
        if (it + 1 < NI) load(it + 1);
        __syncthreads();
        short8 afr[MF], bfr[4];
        #pragma unroll
        for (int mi = 0; mi < MF; ++mi)
            afr[mi] = *(const short8*)&Xs[msub + mi * 16 + ln][q * 8];
        #pragma unroll
        for (int ni = 0; ni < 4; ++ni)
            bfr[ni] = *(const short8*)&Ws[nsub + ni * 16 + ln][q * 8];
        #pragma unroll
        for (int mi = 0; mi < MF; ++mi)
            #pragma unroll
            for (int ni = 0; ni < 4; ++ni)
                acc[mi][ni] = __builtin_amdgcn_mfma_f32_16x16x32_bf16(
                    afr[mi], bfr[ni], acc[mi][ni], 0, 0, 0);
    }

    #pragma unroll
    for (int ni = 0; ni < 4; ++ni) {
        const int o = o0 + nsub + ni * 16 + ln;
        const float bv = bias[o];
        #pragma unroll
        for (int mi = 0; mi < MF; ++mi) {
            const int t = t0 + msub + mi * 16 + q * 4;
            if (MODE == 0) {
                f32x4 v;
                #pragma unroll
                for (int r = 0; r < 4; ++r) v[r] = acc[mi][ni][r] + bv;
                *(f32x4*)((float*)Out + ((size_t)b * O + o) * TT + t) = v;
            } else {
                ushort* Op = (ushort*)Out;
                const int which = o >> 9, oo = o & 511;
                if (which < 2) {
                    #pragma unroll
                    for (int r = 0; r < 4; ++r)
                        Op[(size_t)which * BCTS + ((size_t)(b * TT) + t + r) * CC + oo] =
                            f2bs(acc[mi][ni][r] + bv);
                } else {
                    ushort tmp[4];
                    #pragma unroll
                    for (int r = 0; r < 4; ++r) tmp[r] = f2bs(acc[mi][ni][r] + bv);
                    *(uint2*)&Op[2 * BCTS + ((size_t)(b * CC) + oo) * TT + t] =
                        *(const uint2*)tmp;
                }
            }
        }
    }
}

// ---------------------------------------------------------------------------
// Conv GEMM with halo-staged X: all 3 taps computed from one LDS tile.
//  D[t][o] = sum_{tap,c in kz-range} Xin[b][t+tap-1][c] * Wt[tap][o][c]
// MODE 1: Out bf16 [B,T,O] = relu(D + bias) * mask[t]        (conv1)
// MODE 3: Out fp32 [B,O,T] partial = D  (raw; reduce in addln)  (conv2)
template <int TN, int KSPLIT, int MODE>
__global__ __launch_bounds__(256) void conv_gemm(const ushort* __restrict__ Wt,
                                                 const float* __restrict__ bias,
                                                 const ushort* __restrict__ Xin,
                                                 void* __restrict__ Out,
                                                 const float* __restrict__ mask,
                                                 int O, int K) {
    const int blk = blockIdx.x;
    const int b = blk >> 2;
    const int t0 = (blk & 3) * 128;
    const int o0 = blockIdx.y * TN;
    const int kz = (KSPLIT > 1) ? blockIdx.z : 0;
    const int tid = threadIdx.x;
    const int wid = tid >> 6, lane = tid & 63, ln = lane & 15, q = lane >> 4;
    constexpr int MF = (TN == 128) ? 4 : 2;
    constexpr int TSH = (TN == 128) ? 7 : 6;
    const int msub = (TN == 128) ? (wid & 1) * 64 : wid * 32;
    const int nsub = (TN == 128) ? (wid >> 1) * 64 : 0;

    __shared__ ushort Xs[130][40];      // rows t0-1 .. t0+128
    __shared__ ushort Ws[3 * TN][40];   // [tap*TN + o][c]

    f32x4 acc[MF][4] = {};

    const int Kc = K / KSPLIT;
    const int cbase = kz * Kc;
    const int NC = Kc >> 5;

    const int rx = tid >> 1;            // X main row 0..127
    const int cx = (tid & 1) << 4;
    const int rw0 = tid >> 2;           // W row stepper
    const int cw = (tid & 3) << 3;

    const ushort* Xb = Xin + (size_t)b * TT * K;

    for (int cc = 0; cc < NC; ++cc) {
        const int c0 = cbase + (cc << 5);
        __syncthreads();
        {   // X main rows (always in range: t0+rx in [0,TT))
            const ushort* xp = Xb + (size_t)(t0 + rx) * K + c0 + cx;
            *(uint4*)&Xs[rx + 1][cx] = *(const uint4*)xp;
            *(uint4*)&Xs[rx + 1][cx + 8] = *(const uint4*)(xp + 8);
        }
        if (tid < 8) {   // halo rows t0-1 and t0+128 (zero out of range)
            const int hr = (tid < 4) ? -1 : 128;
            const int cu = (tid & 3) << 3;
            const int tg = t0 + hr;
            uint4 v = make_uint4(0u, 0u, 0u, 0u);
            if (tg >= 0 && tg < TT)
                v = *(const uint4*)(Xb + (size_t)tg * K + c0 + cu);
            *(uint4*)&Xs[hr + 1][cu] = v;
        }
        #pragma unroll
        for (int j = 0; j < 3 * TN / 64; ++j) {   // W: 3*TN rows
            const int r = rw0 + j * 64;
            const int tap = r >> TSH, o = r & (TN - 1);
            const ushort* wp = Wt + ((size_t)(tap * O + o0 + o)) * K + c0 + cw;
            *(uint4*)&Ws[r][cw] = *(const uint4*)wp;
        }
        __syncthreads();
        #pragma unroll
        for (int tap = 0; tap < 3; ++tap) {
            short8 afr[MF], bfr[4];
            #pragma unroll
            for (int mi = 0; mi < MF; ++mi)
                afr[mi] = *(const short8*)&Xs[msub + mi * 16 + ln + tap][q * 8];
            #pragma unroll
            for (int ni = 0; ni < 4; ++ni)
                bfr[ni] = *(const short8*)&Ws[tap * TN + nsub + ni * 16 + ln][q * 8];
            #pragma unroll
            for (int mi = 0; mi < MF; ++mi)
                #pragma unroll
                for (int ni = 0; ni < 4; ++ni)
                    acc[mi][ni] = __builtin_amdgcn_mfma_f32_16x16x32_bf16(
                        afr[mi], bfr[ni], acc[mi][ni], 0, 0, 0);
        }
    }

    #pragma unroll
    for (int ni = 0; ni < 4; ++ni) {
        const int o = o0 + nsub + ni * 16 + ln;
        #pragma unroll
        for (int mi = 0; mi < MF; ++mi) {
            const int t = t0 + msub + mi * 16 + q * 4;
            if (MODE == 1) {
                const float bv = bias[o];
                ushort* Op = (ushort*)Out;
                #pragma unroll
                for (int r = 0; r < 4; ++r) {
                    float v = fmaxf(acc[mi][ni][r] + bv, 0.f) * mask[b * TT + t + r];
                    Op[((size_t)(b * TT) + t + r) * (size_t)O + o] = f2bs(v);
                }
            } else {
                float* Op = (float*)Out + (size_t)kz * BCTS;
                *(f32x4*)(Op + ((size_t)b * O + o) * TT + t) = acc[mi][ni];
            }
        }
    }
}

// ---------------------------------------------------------------------------
// Fused relative-position attention (as round 7).
__global__ __launch_bounds__(256) void fattn_kernel(const ushort* __restrict__ qkvt,
                                                    const float* __restrict__ mask,
                                                    const float* __restrict__ erk,
                                                    const float* __restrict__ erv,
                                                    ushort* __restrict__ xto) {
    const int t0 = blockIdx.x * 64;
    const int bh = blockIdx.y;
    const int b = bh >> 3, h = bh & 7;
    const int tid = threadIdx.x;
    const int wm = tid >> 6;
    const int lane = tid & 63;
    const int ln = lane & 15;
    const int q4 = lane >> 4;

    __shared__ ushort Qs[64][72];
    __shared__ ushort Ks[64][72];
    __shared__ ushort Vs[64][72];
    __shared__ ushort Ps[64][72];
    __shared__ float rel[64][2 * WW + 1];
    __shared__ float ervs[2 * WW + 1][DKK];
    __shared__ float mtile[64];
    __shared__ float mstile[64];

    const int sr = tid >> 2;
    const int sc = (tid & 3) << 4;

    {
        const ushort* qp = qkvt + ((size_t)(b * TT + t0 + sr) * CC + h * DKK + sc);
        *(uint4*)&Qs[sr][sc] = *(const uint4*)qp;
        *(uint4*)&Qs[sr][sc + 8] = *(const uint4*)(qp + 8);
    }
    if (tid < 64) mtile[tid] = mask[b * TT + t0 + tid];
    for (int idx = tid; idx < (2 * WW + 1) * DKK; idx += 256)
        ervs[idx / DKK][idx % DKK] = erv[idx];
    __syncthreads();

    for (int idx = tid; idx < 64 * (2 * WW + 1); idx += 256) {
        const int t = idx / (2 * WW + 1), w = idx % (2 * WW + 1);
        float s = 0.f;
        for (int d = 0; d < DKK; ++d)
            s += bf2f(Qs[t][d]) * erk[w * DKK + d];
        rel[t][w] = 0.125f * s;
    }
    __syncthreads();

    float m_run[4], l_run[4];
    #pragma unroll
    for (int r = 0; r < 4; ++r) { m_run[r] = -1e30f; l_run[r] = 0.f; }
    f32x4 Oacc[4] = {};
    f32x4 Racc[4] = {};

    for (int s0 = 0; s0 < TT; s0 += 64) {
        {
            const ushort* kp = qkvt + BCTS + ((size_t)(b * TT + s0 + sr) * CC + h * DKK + sc);
            *(uint4*)&Ks[sr][sc] = *(const uint4*)kp;
            *(uint4*)&Ks[sr][sc + 8] = *(const uint4*)(kp + 8);
            const ushort* vp = qkvt + 2 * BCTS + ((size_t)(b * CC + h * DKK + sr) * TT + s0 + sc);
            *(uint4*)&Vs[sr][sc] = *(const uint4*)vp;
            *(uint4*)&Vs[sr][sc + 8] = *(const uint4*)(vp + 8);
        }
        if (tid < 64) mstile[tid] = mask[b * TT + s0 + tid];
        __syncthreads();

        f32x4 accs[4] = {};
        {
            short8 a0 = *(const short8*)&Qs[wm * 16 + ln][q4 * 8];
            short8 a1 = *(const short8*)&Qs[wm * 16 + ln][32 + q4 * 8];
            #pragma unroll
            for (int ni = 0; ni < 4; ++ni) {
                short8 b0 = *(const short8*)&Ks[ni * 16 + ln][q4 * 8];
                short8 b1 = *(const short8*)&Ks[ni * 16 + ln][32 + q4 * 8];
                accs[ni] = __builtin_amdgcn_mfma_f32_16x16x32_bf16(a0, b0, accs[ni], 0, 0, 0);
                accs[ni] = __builtin_amdgcn_mfma_f32_16x16x32_bf16(a1, b1, accs[ni], 0, 0, 0);
            }
        }

        float mx[4];
        #pragma unroll
        for (int r = 0; r < 4; ++r) {
            const int tl = wm * 16 + q4 * 4 + r;
            const float mt = mtile[tl];
            float best = -1e30f;
            #pragma unroll
            for (int ni = 0; ni < 4; ++ni) {
                const int sl = ni * 16 + ln;
                const int wb = (s0 + sl) - (t0 + tl) + WW;
                float v = accs[ni][r] * 0.125f;
                if ((unsigned)wb <= 2u * WW) v += rel[tl][wb];
                if (mt * mstile[sl] == 0.f) v = -1e4f;
                accs[ni][r] = v;
                best = fmaxf(best, v);
            }
            #pragma unroll
            for (int off = 8; off >= 1; off >>= 1)
                best = fmaxf(best, __shfl_xor(best, off, 64));
            mx[r] = best;
        }

        #pragma unroll
        for (int r = 0; r < 4; ++r) {
            const float mnew = fmaxf(m_run[r], mx[r]);
            const float alpha = __expf(m_run[r] - mnew);
            m_run[r] = mnew;
            float rsum = 0.f;
            #pragma unroll
            for (int ni = 0; ni < 4; ++ni) {
                const float p = __expf(accs[ni][r] - mnew);
                accs[ni][r] = p;
                rsum += p;
            }
            #pragma unroll
            for (int off = 8; off >= 1; off >>= 1)
                rsum += __shfl_xor(rsum, off, 64);
            l_run[r] = l_run[r] * alpha + rsum;
            #pragma unroll
            for (int ni = 0; ni < 4; ++ni) {
                Oacc[ni][r] *= alpha;
                Racc[ni][r] *= alpha;
            }
        }

        #pragma unroll
        for (int ni = 0; ni < 4; ++ni)
            #pragma unroll
            for (int r = 0; r < 4; ++r)
                Ps[wm * 16 + q4 * 4 + r][ni * 16 + ln] = f2bs(accs[ni][r]);
        __syncthreads();

        {
            short8 a0 = *(const short8*)&Ps[wm * 16 + ln][q4 * 8];
            short8 a1 = *(const short8*)&Ps[wm * 16 + ln][32 + q4 * 8];
            #pragma unroll
            for (int ni = 0; ni < 4; ++ni) {
                short8 b0 = *(const short8*)&Vs[ni * 16 + ln][q4 * 8];
                short8 b1 = *(const short8*)&Vs[ni * 16 + ln][32 + q4 * 8];
                Oacc[ni] = __builtin_amdgcn_mfma_f32_16x16x32_bf16(a0, b0, Oacc[ni], 0, 0, 0);
                Oacc[ni] = __builtin_amdgcn_mfma_f32_16x16x32_bf16(a1, b1, Oacc[ni], 0, 0, 0);
            }
        }

        if (s0 + 63 >= t0 - WW && s0 <= t0 + 63 + WW) {
            #pragma unroll
            for (int r = 0; r < 4; ++r) {
                const int tl = wm * 16 + q4 * 4 + r;
                const int tg = t0 + tl;
                for (int w = 0; w <= 2 * WW; ++w) {
                    const int sl = tg + w - WW - s0;
                    if ((unsigned)sl < 64u) {
                        const float p = bf2f(Ps[tl][sl]);
                        #pragma unroll
                        for (int ni = 0; ni < 4; ++ni)
                            Racc[ni][r] += p * ervs[w][ni * 16 + ln];
                    }
                }
            }
        }
        __syncthreads();
    }

    #pragma unroll
    for (int ni = 0; ni < 4; ++ni) {
        const int d = ni * 16 + ln;
        #pragma unroll
        for (int r = 0; r < 4; ++r) {
            const int t = t0 + wm * 16 + q4 * 4 + r;
            xto[((size_t)(b * TT) + t) * CC + h * DKK + d] =
                f2bs((Oacc[ni][r] + Racc[ni][r]) / l_run[r]);
        }
    }
}

// ---------------------------------------------------------------------------
// x = LN(x + y*(maskY?m:1)), y = p0 (+ p1) (+ biasc[c]); emits Xt bf16 [B,T,C].
__global__ __launch_bounds__(128) void addln_kernel(float* __restrict__ x,
                                                    const float* __restrict__ p0,
                                                    const float* __restrict__ p1,
                                                    const float* __restrict__ biasc,
                                                    const float* __restrict__ g,
                                                    const float* __restrict__ bt,
                                                    const float* __restrict__ mask,
                                                    int maskY,
                                                    ushort* __restrict__ xtout,
                                                    int maskOut) {
    const int b = blockIdx.x / TT;
    const int t = blockIdx.x % TT;
    const float m = mask[b * TT + t];
    const float mv = maskY ? m : 1.f;
    const float mo = maskOut ? m : 1.f;
    const int tid = threadIdx.x;
    float vals[CC / 128];
    float s = 0.f, s2 = 0.f;
    #pragma unroll
    for (int u = 0; u < CC / 128; ++u) {
        const int c = tid + u * 128;
        const size_t idx = ((size_t)b * CC + c) * TT + t;
        float y = p0[idx];
        if (p1) y += p1[idx];
        if (biasc) y += biasc[c];
        const float v = x[idx] + y * mv;
        vals[u] = v;
        s += v;
        s2 += v * v;
    }
    __shared__ float ws[2], ws2[2];
    const int wid = tid >> 6, lane = tid & 63;
    s = wave_sum(s);
    s2 = wave_sum(s2);
    if (lane == 0) { ws[wid] = s; ws2[wid] = s2; }
    __syncthreads();
    const float tot = ws[0] + ws[1];
    const float tot2 = ws2[0] + ws2[1];
    const float mean = tot * (1.f / CC);
    const float var = tot2 * (1.f / CC) - mean * mean;
    const float rstd = rsqrtf(var + 1e-5f);
    #pragma unroll
    for (int u = 0; u < CC / 128; ++u) {
        const int c = tid + u * 128;
        const size_t idx = ((size_t)b * CC + c) * TT + t;
        const float outv = (vals[u] - mean) * rstd * g[c] + bt[c];
        x[idx] = outv;
        xtout[((size_t)(b * TT) + t) * CC + c] = f2bs(outv * mo);
    }
}

// ---------------------------------------------------------------------------
extern "C" void kernel_launch(void* const* d_in, const int* in_sizes, int n_in,
                              void* d_out, int out_size, void* d_ws, size_t ws_size,
                              hipStream_t stream) {
    const float* x_in = (const float*)d_in[0];
    const float* mask = (const float*)d_in[1];
    const float* Wq = (const float*)d_in[2];
    const float* bq = (const float*)d_in[3];
    const float* Wk = (const float*)d_in[4];
    const float* bk = (const float*)d_in[5];
    const float* Wv = (const float*)d_in[6];
    const float* bv = (const float*)d_in[7];
    const float* Wo = (const float*)d_in[8];
    const float* bo = (const float*)d_in[9];
    const float* erk = (const float*)d_in[10];
    const float* erv = (const float*)d_in[11];
    const float* g1 = (const float*)d_in[12];
    const float* b1 = (const float*)d_in[13];
    const float* g2 = (const float*)d_in[14];
    const float* b2 = (const float*)d_in[15];
    const float* W1 = (const float*)d_in[16];
    const float* bf1 = (const float*)d_in[17];
    const float* W2 = (const float*)d_in[18];
    const float* bf2 = (const float*)d_in[19];

    // ws (MiB): xf 8 | Xt 4 | qkvt 12 | Xto 4 | parts 16 (p0,p1) | Midt 16 |
    //           weights ~14  => ~74 total
    float* xf = (float*)d_ws;
    ushort* Xt = (ushort*)(xf + BCTS);
    ushort* qkvt = Xt + BCTS;
    ushort* Xto = qkvt + 3 * BCTS;
    float* parts = (float*)(Xto + BCTS);         // p0 | p1 contiguous
    ushort* Midt = (ushort*)(parts + 2 * BCTS);  // [B,T,F] bf16
    ushort* Wqkv = Midt + 4 * BCTS;
    float* bqkv = (float*)(Wqkv + (size_t)1536 * 512);
    ushort* Wot = (ushort*)(bqkv + 1536);
    ushort* W1t = Wot + (size_t)CC * CC;
    ushort* W2t = W1t + (size_t)3 * FF * CC;

    const int eltBlocks = (int)((BCTS + 255) / 256);
    init_kernel<<<eltBlocks, 256, 0, stream>>>(x_in, mask, xf);
    trans_kernel<<<dim3(TT / 32, CC / 32, BB), 256, 0, stream>>>(xf, Xt);

    const size_t nW = 786432 + 262144 + 3145728 + 3145728;
    const int wcvtBlocks = (int)((nW + 255) / 256);

    for (int L = 0; L < NLAYERS; ++L) {
        wcvt_layer<<<wcvtBlocks, 256, 0, stream>>>(
            Wq + (size_t)L * CC * CC, Wk + (size_t)L * CC * CC, Wv + (size_t)L * CC * CC,
            bq + (size_t)L * CC, bk + (size_t)L * CC, bv + (size_t)L * CC,
            Wo + (size_t)L * CC * CC,
            W1 + (size_t)L * 3 * FF * CC, W2 + (size_t)L * 3 * FF * CC,
            Wqkv, bqkv, Wot, W1t, W2t);

        // fused QKV (N=1536)
        gemm128<2, 128><<<dim3(32, 12), 256, 0, stream>>>(
            Wqkv, bqkv, Xt, qkvt, mask, 1536, CC, 1, 4);

        // fused attention
        fattn_kernel<<<dim3(TT / 64, BB * HH), 256, 0, stream>>>(
            qkvt, mask, erk + (size_t)L * (2 * WW + 1) * DKK,
            erv + (size_t)L * (2 * WW + 1) * DKK, Xto);

        // O-projection + residual LN (emits masked Xt for conv1)
        gemm128<0, 64><<<dim3(32, 8), 256, 0, stream>>>(
            Wot, bo + (size_t)L * CC, Xto, parts, mask, CC, CC, 1, 4);
        addln_kernel<<<BB * TT, 128, 0, stream>>>(
            xf, parts, nullptr, nullptr,
            g1 + (size_t)L * CC, b1 + (size_t)L * CC, mask, 0, Xt, 1);

        // FFN: conv1 (halo, 3 taps from LDS) -> conv2 (halo + K-split) -> LN
        conv_gemm<128, 1, 1><<<dim3(32, FF / 128, 1), 256, 0, stream>>>(
            W1t, bf1 + (size_t)L * FF, Xt, Midt, mask, FF, CC);
        conv_gemm<64, 2, 3><<<dim3(32, CC / 64, 2), 256, 0, stream>>>(
            W2t, nullptr, Midt, parts, mask, CC, FF);
        addln_kernel<<<BB * TT, 128, 0, stream>>>(
            xf, parts, parts + BCTS, bf2 + (size_t)L * CC,
            g2 + (size_t)L * CC, b2 + (size_t)L * CC, mask, 1, Xt, 0);
    }

    final_kernel<<<eltBlocks, 256, 0, stream>>>(xf, mask, (float*)d_out);
}